// Round 28
// baseline (1935.447 us; speedup 1.0000x reference)
//
#include <hip/hip_runtime.h>
#include <hip/hip_bf16.h>

#define NND 20000
#define NE  200000
#define NT  800000

#define SW256(row) (((row) & 7) << 4)
#define SW128(row) (((row) & 7) << 4)

typedef short  s16x8 __attribute__((ext_vector_type(8)));
typedef float  f32x4 __attribute__((ext_vector_type(4)));

__device__ __forceinline__ float silu_f(float v) {
    return v * __builtin_amdgcn_rcpf(1.0f + __expf(-v));
}

__device__ __forceinline__ ushort f2bf(float f) {
    uint u = __float_as_uint(f);
    uint r = (u + 0x7FFFu + ((u >> 16) & 1u)) >> 16;   // RTNE
    return (ushort)r;
}
__device__ __forceinline__ float bf2f(ushort u) {
    return __uint_as_float(((uint)u) << 16);
}
__device__ __forceinline__ uint f2bf_pk(float a, float b) {
    __hip_bfloat162 h = __float22bfloat162_rn(make_float2(a, b));
    return *(uint*)&h;
}
__device__ __forceinline__ void store_bf4(void* p, float v0, float v1, float v2, float v3) {
    uint2 o;
    o.x = f2bf_pk(v0, v1);
    o.y = f2bf_pk(v2, v3);
    *(uint2*)p = o;
}

// ---------------------------------------------------------------------------
// Bessel basis
// ---------------------------------------------------------------------------
__global__ void rbf_kernel(const float* __restrict__ dist, const float* __restrict__ freq,
                           float* __restrict__ rbf, int E)
{
    int e = blockIdx.x * blockDim.x + threadIdx.x;
    if (e >= E) return;
    float d = dist[e] * 0.2f;
    float d5 = d * d; d5 = d5 * d5 * d;
    float env = 1.0f / d + (-28.0f) * d5 + 48.0f * d5 * d + (-21.0f) * d5 * d * d;
    env = (d < 1.0f) ? env : 0.0f;
    float fr[6];
    #pragma unroll
    for (int r = 0; r < 6; ++r) fr[r] = freq[r];
    #pragma unroll
    for (int r = 0; r < 6; ++r)
        rbf[(size_t)e * 6 + r] = env * sinf(fr[r] * d);
}

// ---------------------------------------------------------------------------
// Weight transpose+convert (generic) and 7-way merged version
// ---------------------------------------------------------------------------
__global__ void twt_kernel(const float* __restrict__ W, ushort* __restrict__ Wt,
                           int CIN, int COUT, int total)
{
    int idx = blockIdx.x * 256 + threadIdx.x;
    if (idx >= total) return;
    int per = CIN * COUT;
    int b = idx / per, r = idx % per;
    int k = r / COUT, c = r % COUT;
    Wt[(size_t)b * per + (size_t)c * CIN + k] = f2bf(W[idx]);
}

__global__ void twt7_kernel(const float* __restrict__ s0, const float* __restrict__ s1,
                            const float* __restrict__ s2, const float* __restrict__ s3,
                            const float* __restrict__ s4, const float* __restrict__ s5,
                            const float* __restrict__ s6, ushort* __restrict__ dst)
{
    int idx = blockIdx.x * 256 + threadIdx.x;     // 7 * 65536 total
    int which = idx >> 16;
    int r = idx & 65535;
    const float* s = (which == 0) ? s0 : (which == 1) ? s1 : (which == 2) ? s2 :
                     (which == 3) ? s3 : (which == 4) ? s4 : (which == 5) ? s5 : s6;
    int b = r >> 14;
    int rr = r & 16383;
    int k = rr >> 7, c = rr & 127;
    dst[(size_t)which * 65536 + b * 16384 + c * 128 + k] = f2bf(s[r]);
}

// ---------------------------------------------------------------------------
// bf16 MFMA linear (embedding t3 only). CIN=COUT=128.
// ---------------------------------------------------------------------------
template<int CIN, int COUT, int MODE, typename IT, typename ET, typename OT>
__global__ __launch_bounds__(256) void mfma_lin_kernel(
    const IT* __restrict__ x, const ushort* __restrict__ Wt,
    const float* __restrict__ bias, const ET* __restrict__ extra,
    OT* __restrict__ y, int M)
{
    constexpr int MT = 64;
    constexpr int NF = COUT / 16;
    constexpr int KS = CIN / 32;
    constexpr int PITCH = CIN * 2;
    __shared__ ushort As_u[MT * CIN];
    __shared__ ushort Ws_u[COUT * CIN];
    char* As = (char*)As_u;
    char* Ws = (char*)Ws_u;
    const int tid = threadIdx.x;
    const int row0 = blockIdx.x * MT;
    const bool full = (row0 + MT <= M);

    constexpr int ACH = MT * CIN / 8;
    for (int c = tid; c < ACH; c += 256) {
        int row = c / (CIN / 8);
        int kc  = c % (CIN / 8);
        int grow = row0 + row;
        s16x8 v;
        if (full || grow < M) {
            if constexpr (sizeof(IT) == 4) {
                const float* src = (const float*)x + (size_t)grow * CIN + kc * 8;
                float4 f0 = *(const float4*)(src);
                float4 f1 = *(const float4*)(src + 4);
                v[0] = (short)f2bf(f0.x); v[1] = (short)f2bf(f0.y);
                v[2] = (short)f2bf(f0.z); v[3] = (short)f2bf(f0.w);
                v[4] = (short)f2bf(f1.x); v[5] = (short)f2bf(f1.y);
                v[6] = (short)f2bf(f1.z); v[7] = (short)f2bf(f1.w);
            } else {
                v = *(const s16x8*)((const ushort*)x + (size_t)grow * CIN + kc * 8);
            }
        } else {
            #pragma unroll
            for (int u = 0; u < 8; ++u) v[u] = 0;
        }
        *(s16x8*)(As + ((row * PITCH + kc * 16) ^ SW256(row))) = v;
    }
    constexpr int WCH = COUT * CIN / 8;
    for (int c = tid; c < WCH; c += 256) {
        int col = c / (CIN / 8);
        int kc  = c % (CIN / 8);
        s16x8 v = *(const s16x8*)(Wt + (size_t)col * CIN + kc * 8);
        *(s16x8*)(Ws + ((col * PITCH + kc * 16) ^ SW256(col))) = v;
    }
    __syncthreads();

    const int w = tid >> 6, lane = tid & 63;
    const int l15 = lane & 15, l4 = lane >> 4;
    const int arow = w * 16 + l15;

    f32x4 acc[NF];
    #pragma unroll
    for (int nf = 0; nf < NF; ++nf) acc[nf] = (f32x4){0.f, 0.f, 0.f, 0.f};

    #pragma unroll
    for (int ks = 0; ks < KS; ++ks) {
        const int kbyte = (ks * 32 + l4 * 8) * 2;
        s16x8 a = *(const s16x8*)(As + ((arow * PITCH + kbyte) ^ SW256(arow)));
        #pragma unroll
        for (int nf = 0; nf < NF; ++nf) {
            int col = nf * 16 + l15;
            s16x8 bf = *(const s16x8*)(Ws + ((col * PITCH + kbyte) ^ SW256(col)));
            acc[nf] = __builtin_amdgcn_mfma_f32_16x16x32_bf16(bf, a, acc[nf], 0, 0, 0);
        }
    }

    const int grow = row0 + w * 16 + l15;
    if (grow < M) {
        #pragma unroll
        for (int nf = 0; nf < NF; ++nf) {
            int c0 = nf * 16 + l4 * 4;
            float4 bv = make_float4(0.f, 0.f, 0.f, 0.f);
            if (bias) bv = *(const float4*)(bias + c0);
            float v0 = acc[nf][0] + bv.x, v1 = acc[nf][1] + bv.y;
            float v2 = acc[nf][2] + bv.z, v3 = acc[nf][3] + bv.w;
            if constexpr (MODE & 1) {
                v0 = silu_f(v0); v1 = silu_f(v1); v2 = silu_f(v2); v3 = silu_f(v3);
            }
            if constexpr ((MODE & 4) != 0) {
                if constexpr (sizeof(ET) == 4) {
                    float4 ex = *(const float4*)((const float*)extra + (size_t)grow * COUT + c0);
                    v0 += ex.x; v1 += ex.y; v2 += ex.z; v3 += ex.w;
                } else {
                    ushort4 ex = *(const ushort4*)((const ushort*)extra + (size_t)grow * COUT + c0);
                    v0 += bf2f(ex.x); v1 += bf2f(ex.y); v2 += bf2f(ex.z); v3 += bf2f(ex.w);
                }
            }
            if constexpr (sizeof(OT) == 4) {
                float* o = (float*)y + (size_t)grow * COUT + c0;
                if constexpr (MODE & 8) {
                    float4 cur = *(const float4*)o;
                    v0 += cur.x; v1 += cur.y; v2 += cur.z; v3 += cur.w;
                }
                *(float4*)o = make_float4(v0, v1, v2, v3);
            } else {
                store_bf4((ushort*)y + (size_t)grow * COUT + c0, v0, v1, v2, v3);
            }
        }
    }
}

// ---------------------------------------------------------------------------
// FRONT fused with Wdown register-prefetch (round-25 proven version).
// ---------------------------------------------------------------------------
__global__ __launch_bounds__(256) void mfma_front_kernel(
    const ushort* __restrict__ x,
    const ushort* __restrict__ Wt1, const ushort* __restrict__ Wt2,
    const ushort* __restrict__ Wtd,
    const float* __restrict__ b1, const float* __restrict__ b2,
    const float* __restrict__ rbf, const float* __restrict__ W1r,
    const float* __restrict__ W2r,
    ushort* __restrict__ y1, ushort* __restrict__ yd, int M)
{
    constexpr int PITCH = 256;
    __shared__ ushort A_u[64 * 128];
    __shared__ ushort W1_u[128 * 128];
    __shared__ ushort W2_u[128 * 128];
    char* A = (char*)A_u;
    char* W1s = (char*)W1_u;
    char* W2s = (char*)W2_u;
    const int tid = threadIdx.x;
    const int row0 = blockIdx.x * 64;

    for (int c = tid; c < 1024; c += 256) {
        int row = c >> 4, kc = c & 15;
        s16x8 v = *(const s16x8*)(x + (size_t)(row0 + row) * 128 + kc * 8);
        *(s16x8*)(A + ((row * PITCH + kc * 16) ^ SW256(row))) = v;
    }
    for (int c = tid; c < 2048; c += 256) {
        int col = c >> 4, kc = c & 15;
        int o = (col * PITCH + kc * 16) ^ SW256(col);
        *(s16x8*)(W1s + o) = *(const s16x8*)(Wt1 + (size_t)col * 128 + kc * 8);
        *(s16x8*)(W2s + o) = *(const s16x8*)(Wt2 + (size_t)col * 128 + kc * 8);
    }
    s16x8 wdreg[4];
    #pragma unroll
    for (int i = 0; i < 4; ++i) {
        int c = tid + i * 256;
        wdreg[i] = *(const s16x8*)(Wtd + (size_t)(c >> 4) * 128 + (c & 15) * 8);
    }
    __syncthreads();

    const int w = tid >> 6, lane = tid & 63;
    const int l15 = lane & 15, l4 = lane >> 4;
    const int arow = w * 16 + l15;

    f32x4 acc1[8], acc2[8];
    #pragma unroll
    for (int nf = 0; nf < 8; ++nf) {
        acc1[nf] = (f32x4){0.f, 0.f, 0.f, 0.f};
        acc2[nf] = (f32x4){0.f, 0.f, 0.f, 0.f};
    }
    #pragma unroll
    for (int ks = 0; ks < 4; ++ks) {
        const int kbyte = (ks * 32 + l4 * 8) * 2;
        s16x8 a = *(const s16x8*)(A + ((arow * PITCH + kbyte) ^ SW256(arow)));
        #pragma unroll
        for (int nf = 0; nf < 8; ++nf) {
            int col = nf * 16 + l15;
            int o = (col * PITCH + kbyte) ^ SW256(col);
            s16x8 bf1 = *(const s16x8*)(W1s + o);
            s16x8 bf2 = *(const s16x8*)(W2s + o);
            acc1[nf] = __builtin_amdgcn_mfma_f32_16x16x32_bf16(bf1, a, acc1[nf], 0, 0, 0);
            acc2[nf] = __builtin_amdgcn_mfma_f32_16x16x32_bf16(bf2, a, acc2[nf], 0, 0, 0);
        }
    }
    __syncthreads();

    const int grow = row0 + arow;
    float rv[6];
    #pragma unroll
    for (int q = 0; q < 6; ++q) rv[q] = rbf[(size_t)grow * 6 + q];
    float t8[8];
    #pragma unroll
    for (int p = 0; p < 8; ++p) {
        float s = 0.f;
        #pragma unroll
        for (int q = 0; q < 6; ++q) s += rv[q] * W1r[q * 8 + p];
        t8[p] = s;
    }
    #pragma unroll
    for (int nf = 0; nf < 8; ++nf) {
        int c0 = nf * 16 + l4 * 4;
        float4 bb1 = *(const float4*)(b1 + c0);
        float4 bb2 = *(const float4*)(b2 + c0);
        store_bf4(y1 + (size_t)grow * 128 + c0,
                  silu_f(acc1[nf][0] + bb1.x), silu_f(acc1[nf][1] + bb1.y),
                  silu_f(acc1[nf][2] + bb1.z), silu_f(acc1[nf][3] + bb1.w));
        float r0 = 0.f, r1 = 0.f, r2 = 0.f, r3 = 0.f;
        #pragma unroll
        for (int p = 0; p < 8; ++p) {
            float4 wq = *(const float4*)(W2r + p * 128 + c0);
            float tp = t8[p];
            r0 += tp * wq.x; r1 += tp * wq.y; r2 += tp * wq.z; r3 += tp * wq.w;
        }
        store_bf4(A + ((arow * PITCH + c0 * 2) ^ SW256(arow)),
                  silu_f(acc2[nf][0] + bb2.x) * r0, silu_f(acc2[nf][1] + bb2.y) * r1,
                  silu_f(acc2[nf][2] + bb2.z) * r2, silu_f(acc2[nf][3] + bb2.w) * r3);
    }
    #pragma unroll
    for (int i = 0; i < 4; ++i) {
        int c = tid + i * 256;
        int col = c >> 4, kc = c & 15;
        *(s16x8*)(W1s + ((col * PITCH + kc * 16) ^ SW256(col))) = wdreg[i];
    }
    __syncthreads();

    f32x4 accd[4];
    #pragma unroll
    for (int nf = 0; nf < 4; ++nf) accd[nf] = (f32x4){0.f, 0.f, 0.f, 0.f};
    #pragma unroll
    for (int ks = 0; ks < 4; ++ks) {
        const int kbyte = (ks * 32 + l4 * 8) * 2;
        s16x8 a = *(const s16x8*)(A + ((arow * PITCH + kbyte) ^ SW256(arow)));
        #pragma unroll
        for (int nf = 0; nf < 4; ++nf) {
            int col = nf * 16 + l15;
            s16x8 bf = *(const s16x8*)(W1s + ((col * PITCH + kbyte) ^ SW256(col)));
            accd[nf] = __builtin_amdgcn_mfma_f32_16x16x32_bf16(bf, a, accd[nf], 0, 0, 0);
        }
    }
    #pragma unroll
    for (int nf = 0; nf < 4; ++nf) {
        int c0 = nf * 16 + l4 * 4;
        store_bf4(yd + (size_t)grow * 64 + c0,
                  silu_f(accd[nf][0]), silu_f(accd[nf][1]),
                  silu_f(accd[nf][2]), silu_f(accd[nf][3]));
    }
}

// ---------------------------------------------------------------------------
// BACK fused, wave-column-split, 64-row tiles, double-buffered weight
// prefetch + register prefetch of xji (P1) and x (P4) epilogue operands.
// ---------------------------------------------------------------------------
__global__ __launch_bounds__(256) void mfma_back_kernel(
    const ushort* __restrict__ go, const ushort* __restrict__ xji,
    const ushort* __restrict__ x,
    const ushort* __restrict__ Wup, const ushort* __restrict__ Wrb1,
    const ushort* __restrict__ Wrb2, const ushort* __restrict__ Wlin,
    const ushort* __restrict__ Wra1, const ushort* __restrict__ Wra2,
    const float* __restrict__ b_rb1, const float* __restrict__ b_rb2,
    const float* __restrict__ b_lin, const float* __restrict__ b_ra1,
    const float* __restrict__ b_ra2,
    ushort* __restrict__ xout, int M)
{
    __shared__ ushort A_u[64 * 128];
    __shared__ ushort T_u[64 * 128];
    char* A  = (char*)A_u;
    char* Tb = (char*)T_u;
    const int tid = threadIdx.x;
    const int row0 = blockIdx.x * 64;
    const int w = tid >> 6, lane = tid & 63;
    const int l15 = lane & 15, l4 = lane >> 4;
    const int colbase = w * 32;

    f32x4 acc[8];
    s16x8 wfA[8], wfB[8];
    ushort4 xr[8];

    auto zero_acc = [&]() {
        #pragma unroll
        for (int i = 0; i < 8; ++i) acc[i] = (f32x4){0.f, 0.f, 0.f, 0.f};
    };
    auto load_w8 = [&](s16x8* wf, const ushort* Wg) {
        #pragma unroll
        for (int nfi = 0; nfi < 2; ++nfi)
            #pragma unroll
            for (int ks = 0; ks < 4; ++ks)
                wf[nfi * 4 + ks] = *(const s16x8*)(
                    Wg + (size_t)(colbase + nfi * 16 + l15) * 128 + ks * 32 + l4 * 8);
    };
    auto load_rows = [&](const ushort* src) {
        #pragma unroll
        for (int rt = 0; rt < 4; ++rt) {
            int grow = row0 + rt * 16 + l15;
            #pragma unroll
            for (int nfi = 0; nfi < 2; ++nfi) {
                int c0 = colbase + nfi * 16 + l4 * 4;
                xr[rt * 2 + nfi] = *(const ushort4*)(src + (size_t)grow * 128 + c0);
            }
        }
    };
    auto run_phase = [&](char* Ab, const s16x8* wf) {
        #pragma unroll
        for (int rt = 0; rt < 4; ++rt) {
            int row = rt * 16 + l15;
            #pragma unroll
            for (int ks = 0; ks < 4; ++ks) {
                s16x8 a = *(const s16x8*)(Ab + ((row * 256 + ks * 64 + l4 * 16) ^ SW256(row)));
                acc[rt * 2 + 0] = __builtin_amdgcn_mfma_f32_16x16x32_bf16(wf[0 * 4 + ks], a, acc[rt * 2 + 0], 0, 0, 0);
                acc[rt * 2 + 1] = __builtin_amdgcn_mfma_f32_16x16x32_bf16(wf[1 * 4 + ks], a, acc[rt * 2 + 1], 0, 0, 0);
            }
        }
    };

    // prologue: stage go tile; load Wup frags; prefetch rb1 weights + xji rows
    s16x8 wfUp[4];
    #pragma unroll
    for (int nfi = 0; nfi < 2; ++nfi)
        #pragma unroll
        for (int ks = 0; ks < 2; ++ks)
            wfUp[nfi * 2 + ks] = *(const s16x8*)(
                Wup + (size_t)(colbase + nfi * 16 + l15) * 64 + ks * 32 + l4 * 8);
    for (int c = tid; c < 512; c += 256) {
        int row = c >> 3, kc = c & 7;
        s16x8 v = *(const s16x8*)(go + (size_t)(row0 + row) * 64 + kc * 8);
        *(s16x8*)(Tb + ((row * 128 + kc * 16) ^ SW128(row))) = v;
    }
    load_w8(wfA, Wrb1);
    load_rows(xji);
    __syncthreads();

    // P1: hdd = xji + silu(go @ Wup)
    zero_acc();
    #pragma unroll
    for (int rt = 0; rt < 4; ++rt) {
        int row = rt * 16 + l15;
        #pragma unroll
        for (int ks = 0; ks < 2; ++ks) {
            s16x8 a = *(const s16x8*)(Tb + ((row * 128 + ks * 64 + l4 * 16) ^ SW128(row)));
            acc[rt * 2 + 0] = __builtin_amdgcn_mfma_f32_16x16x32_bf16(wfUp[0 * 2 + ks], a, acc[rt * 2 + 0], 0, 0, 0);
            acc[rt * 2 + 1] = __builtin_amdgcn_mfma_f32_16x16x32_bf16(wfUp[1 * 2 + ks], a, acc[rt * 2 + 1], 0, 0, 0);
        }
    }
    #pragma unroll
    for (int rt = 0; rt < 4; ++rt) {
        int row = rt * 16 + l15;
        #pragma unroll
        for (int nfi = 0; nfi < 2; ++nfi) {
            int c0 = colbase + nfi * 16 + l4 * 4;
            f32x4 v = acc[rt * 2 + nfi];
            ushort4 xj = xr[rt * 2 + nfi];
            store_bf4(A + ((row * 256 + c0 * 2) ^ SW256(row)),
                      bf2f(xj.x) + silu_f(v[0]), bf2f(xj.y) + silu_f(v[1]),
                      bf2f(xj.z) + silu_f(v[2]), bf2f(xj.w) + silu_f(v[3]));
        }
    }
    __syncthreads();

    // P2: t = silu(hdd@rb1+b1)  A -> Tb   (prefetch rb2 into wfB)
    load_w8(wfB, Wrb2);
    zero_acc();
    run_phase(A, wfA);
    #pragma unroll
    for (int rt = 0; rt < 4; ++rt) {
        int row = rt * 16 + l15;
        #pragma unroll
        for (int nfi = 0; nfi < 2; ++nfi) {
            int c0 = colbase + nfi * 16 + l4 * 4;
            f32x4 v = acc[rt * 2 + nfi];
            float4 bb = *(const float4*)(b_rb1 + c0);
            store_bf4(Tb + ((row * 256 + c0 * 2) ^ SW256(row)),
                      silu_f(v[0] + bb.x), silu_f(v[1] + bb.y),
                      silu_f(v[2] + bb.z), silu_f(v[3] + bb.w));
        }
    }
    __syncthreads();

    // P3: hdd += silu(t@rb2+b2)  Tb -> A   (prefetch lin into wfA, x rows into xr)
    load_w8(wfA, Wlin);
    load_rows(x);
    zero_acc();
    run_phase(Tb, wfB);
    #pragma unroll
    for (int rt = 0; rt < 4; ++rt) {
        int row = rt * 16 + l15;
        #pragma unroll
        for (int nfi = 0; nfi < 2; ++nfi) {
            int c0 = colbase + nfi * 16 + l4 * 4;
            f32x4 v = acc[rt * 2 + nfi];
            float4 bb = *(const float4*)(b_rb2 + c0);
            int ao = (row * 256 + c0 * 2) ^ SW256(row);
            ushort4 h = *(const ushort4*)(A + ao);
            store_bf4(A + ao,
                      bf2f(h.x) + silu_f(v[0] + bb.x), bf2f(h.y) + silu_f(v[1] + bb.y),
                      bf2f(h.z) + silu_f(v[2] + bb.z), bf2f(h.w) + silu_f(v[3] + bb.w));
        }
    }
    __syncthreads();

    // P4: hdd2 = silu(hdd@lin+bl) + x   A -> A   (prefetch ra1 into wfB)
    load_w8(wfB, Wra1);
    zero_acc();
    run_phase(A, wfA);
    __syncthreads();   // all reads of A done before overwrite
    #pragma unroll
    for (int rt = 0; rt < 4; ++rt) {
        int row = rt * 16 + l15;
        #pragma unroll
        for (int nfi = 0; nfi < 2; ++nfi) {
            int c0 = colbase + nfi * 16 + l4 * 4;
            f32x4 v = acc[rt * 2 + nfi];
            float4 bb = *(const float4*)(b_lin + c0);
            ushort4 xv = xr[rt * 2 + nfi];
            store_bf4(A + ((row * 256 + c0 * 2) ^ SW256(row)),
                      silu_f(v[0] + bb.x) + bf2f(xv.x), silu_f(v[1] + bb.y) + bf2f(xv.y),
                      silu_f(v[2] + bb.z) + bf2f(xv.z), silu_f(v[3] + bb.w) + bf2f(xv.w));
        }
    }
    __syncthreads();

    // P5: t = silu(hdd2@ra1+a1)  A -> Tb   (prefetch ra2 into wfA)
    load_w8(wfA, Wra2);
    zero_acc();
    run_phase(A, wfB);
    #pragma unroll
    for (int rt = 0; rt < 4; ++rt) {
        int row = rt * 16 + l15;
        #pragma unroll
        for (int nfi = 0; nfi < 2; ++nfi) {
            int c0 = colbase + nfi * 16 + l4 * 4;
            f32x4 v = acc[rt * 2 + nfi];
            float4 bb = *(const float4*)(b_ra1 + c0);
            store_bf4(Tb + ((row * 256 + c0 * 2) ^ SW256(row)),
                      silu_f(v[0] + bb.x), silu_f(v[1] + bb.y),
                      silu_f(v[2] + bb.z), silu_f(v[3] + bb.w));
        }
    }
    __syncthreads();

    // P6: xout = hdd2 + silu(t@ra2+a2)  Tb -> global
    zero_acc();
    run_phase(Tb, wfA);
    #pragma unroll
    for (int rt = 0; rt < 4; ++rt) {
        int row = rt * 16 + l15;
        int grow = row0 + row;
        #pragma unroll
        for (int nfi = 0; nfi < 2; ++nfi) {
            int c0 = colbase + nfi * 16 + l4 * 4;
            f32x4 v = acc[rt * 2 + nfi];
            float4 bb = *(const float4*)(b_ra2 + c0);
            ushort4 h = *(const ushort4*)(A + ((row * 256 + c0 * 2) ^ SW256(row)));
            store_bf4(xout + (size_t)grow * 128 + c0,
                      bf2f(h.x) + silu_f(v[0] + bb.x), bf2f(h.y) + silu_f(v[1] + bb.y),
                      bf2f(h.z) + silu_f(v[2] + bb.z), bf2f(h.w) + silu_f(v[3] + bb.w));
        }
    }
}

// ---------------------------------------------------------------------------
// Node gather (bf16 output — identical rounding to the old fp32->bf16 stage)
// ---------------------------------------------------------------------------
__global__ __launch_bounds__(256) void node_gather_kernel(
    const float* __restrict__ rbf, const float* __restrict__ Wo,
    const ushort* __restrict__ x, const int* __restrict__ noffs,
    const int* __restrict__ nedge, ushort* __restrict__ node, int N)
{
    const int tid = threadIdx.x;
    const int col = tid & 127;
    const int n = blockIdx.x * 2 + (tid >> 7);
    if (n >= N) return;
    float wo[6];
    #pragma unroll
    for (int q = 0; q < 6; ++q) wo[q] = Wo[q * 128 + col];
    float acc = 0.f;
    const int k0 = noffs[n], k1 = noffs[n + 1];
    for (int k = k0; k < k1; ++k) {
        int e = nedge[k];
        const float* rb = rbf + (size_t)e * 6;
        float t = wo[0] * rb[0] + wo[1] * rb[1] + wo[2] * rb[2]
                + wo[3] * rb[3] + wo[4] * rb[4] + wo[5] * rb[5];
        acc += t * bf2f(x[(size_t)e * 128 + col]);
    }
    node[(size_t)n * 128 + col] = f2bf(acc);
}

// ---------------------------------------------------------------------------
// Fused output block chain — W buffer shrunk to 16 KB (64-col x 128-K chunks)
// => LDS 80 KB => 2 blocks/CU. A/T ping-pong intact. node input is bf16.
// ---------------------------------------------------------------------------
__global__ __launch_bounds__(256) void mfma_out_kernel(
    const ushort* __restrict__ node,
    const ushort* __restrict__ Wup, const ushort* __restrict__ Wlin,
    const float* __restrict__ BL, float* __restrict__ P, int N)
{
    __shared__ ushort A_u[64 * 256];   // 32 KB
    __shared__ ushort T_u[64 * 256];   // 32 KB
    __shared__ ushort W_u[64 * 128];   // 16 KB
    char* A  = (char*)A_u;
    char* Tb = (char*)T_u;
    char* Ws = (char*)W_u;
    const int tid = threadIdx.x;
    const int row0 = blockIdx.x * 64;
    const int w = tid >> 6, lane = tid & 63;
    const int l15 = lane & 15, l4 = lane >> 4;
    const int arow = w * 16 + l15;
    const int grow = row0 + arow;
    const int c_base = l4 * 4;

    f32x4 acc[16];
    s16x8 wreg[4];

    // 64 cols x 128 K chunk (16 KB)
    auto prefetch_w = [&](const ushort* base, int stride) {
        #pragma unroll
        for (int i = 0; i < 4; ++i) {
            int c = tid + i * 256;           // 0..1023
            int col = c >> 4, kc = c & 15;   // col 0..63, k 0..127
            wreg[i] = *(const s16x8*)(base + (size_t)col * stride + kc * 8);
        }
    };
    auto commit_w = [&]() {
        #pragma unroll
        for (int i = 0; i < 4; ++i) {
            int c = tid + i * 256;
            int col = c >> 4, kc = c & 15;
            *(s16x8*)(Ws + ((col * 256 + kc * 16) ^ SW256(col))) = wreg[i];
        }
    };
    auto run4 = [&](char* Ab, int apitch, int kboff, int accoff) {
        #pragma unroll
        for (int ks = 0; ks < 4; ++ks) {
            const int kbw = ks * 64 + l4 * 16;
            s16x8 a = *(const s16x8*)(Ab + ((arow * apitch + kboff + kbw) ^ SW256(arow)));
            #pragma unroll
            for (int nf = 0; nf < 4; ++nf) {
                int col = nf * 16 + l15;
                s16x8 bf = *(const s16x8*)(Ws + ((col * 256 + kbw) ^ SW256(col)));
                acc[accoff + nf] = __builtin_amdgcn_mfma_f32_16x16x32_bf16(bf, a, acc[accoff + nf], 0, 0, 0);
            }
        }
    };

    #pragma unroll
    for (int i = 0; i < 16; ++i) acc[i] = (f32x4){0.f, 0.f, 0.f, 0.f};

    // stage node (bf16) -> Tb
    for (int c = tid; c < 1024; c += 256) {
        int row = c >> 4, kc = c & 15;
        int gr = row0 + row;
        s16x8 v;
        if (gr < N) {
            v = *(const s16x8*)(node + (size_t)gr * 128 + kc * 8);
        } else {
            #pragma unroll
            for (int u = 0; u < 8; ++u) v[u] = 0;
        }
        *(s16x8*)(Tb + ((row * 256 + kc * 16) ^ SW256(row))) = v;
    }
    prefetch_w(Wup, 128);                      // cols 0-63
    __syncthreads();

    // up-proj: 4 chunks of 64 cols (K=128 from Tb)
    for (int cq = 0; cq < 4; ++cq) {
        commit_w();
        if (cq < 3) prefetch_w(Wup + (size_t)(cq + 1) * 64 * 128, 128);
        else        prefetch_w(Wlin, 256);     // first layer chunk (c64=0, kh=0)
        __syncthreads();
        run4(Tb, 256, 0, cq * 4);
        __syncthreads();
    }
    // write up result to A (512B rows)
    #pragma unroll
    for (int nf = 0; nf < 16; ++nf) {
        int c0 = nf * 16 + c_base;
        store_bf4(A + ((arow * 512 + c0 * 2) ^ SW256(arow)),
                  acc[nf][0], acc[nf][1], acc[nf][2], acc[nf][3]);
    }
    __syncthreads();

    char* S = A; char* D = Tb;
    for (int l = 0; l < 3; ++l) {
        #pragma unroll
        for (int i = 0; i < 16; ++i) acc[i] = (f32x4){0.f, 0.f, 0.f, 0.f};
        const ushort* WL = Wlin + (size_t)l * 65536;
        for (int q = 0; q < 8; ++q) {
            int c64 = q & 3, kh = q >> 2;
            commit_w();
            if (q < 7) {
                int nq = q + 1;
                prefetch_w(WL + (size_t)(nq & 3) * 64 * 256 + (size_t)(nq >> 2) * 128, 256);
            } else if (l < 2) {
                prefetch_w(Wlin + (size_t)(l + 1) * 65536, 256);
            }
            __syncthreads();
            run4(S, 512, kh * 256, c64 * 4);
            __syncthreads();
        }
        const float* bl = BL + l * 256;
        if (l < 2) {
            #pragma unroll
            for (int nf = 0; nf < 16; ++nf) {
                int c0 = nf * 16 + c_base;
                float4 bb = *(const float4*)(bl + c0);
                store_bf4(D + ((arow * 512 + c0 * 2) ^ SW256(arow)),
                          silu_f(acc[nf][0] + bb.x), silu_f(acc[nf][1] + bb.y),
                          silu_f(acc[nf][2] + bb.z), silu_f(acc[nf][3] + bb.w));
            }
            __syncthreads();
            char* tmp = S; S = D; D = tmp;
        } else if (grow < N) {
            #pragma unroll
            for (int nf = 0; nf < 16; ++nf) {
                int c0 = nf * 16 + c_base;
                float4 bb = *(const float4*)(bl + c0);
                float* o = P + (size_t)grow * 256 + c0;
                float4 cur = *(const float4*)o;
                *(float4*)o = make_float4(cur.x + silu_f(acc[nf][0] + bb.x),
                                          cur.y + silu_f(acc[nf][1] + bb.y),
                                          cur.z + silu_f(acc[nf][2] + bb.z),
                                          cur.w + silu_f(acc[nf][3] + bb.w));
            }
        }
    }
}

// ---------------------------------------------------------------------------
// Generic fp32-in linear with selectable output type (tiny GEMMs only)
// ---------------------------------------------------------------------------
template<int CIN, int COUT, int MODE, typename OT>
__global__ __launch_bounds__(256) void lin_kernel(
    const float* __restrict__ x, const float* __restrict__ W,
    const float* __restrict__ bias, const float* __restrict__ extra,
    OT* __restrict__ y, int M)
{
    constexpr int MT = 64;
    constexpr int CG = COUT / 4;
    constexpr int RG = 256 / CG;
    constexpr int MR = MT / RG;
    __shared__ float xs[MT * CIN];

    const int row0 = blockIdx.x * MT;
    const int tid  = threadIdx.x;
    const int rem  = M - row0;

    if (rem >= MT) {
        const float4* src = (const float4*)(x + (size_t)row0 * CIN);
        constexpr int TOT4 = (MT * CIN) / 4;
        for (int idx = tid; idx < TOT4; idx += 256)
            ((float4*)xs)[idx] = src[idx];
    } else {
        for (int idx = tid; idx < MT * CIN; idx += 256) {
            int r = idx / CIN;
            xs[idx] = (r < rem) ? x[(size_t)(row0 + r) * CIN + (idx % CIN)] : 0.0f;
        }
    }
    __syncthreads();

    const int cg = tid % CG, rg = tid / CG;
    const int c0 = cg * 4;
    float acc[MR][4];
    #pragma unroll
    for (int m = 0; m < MR; ++m) { acc[m][0]=0; acc[m][1]=0; acc[m][2]=0; acc[m][3]=0; }

    for (int k = 0; k < CIN; ++k) {
        float4 w = *(const float4*)(W + (size_t)k * COUT + c0);
        #pragma unroll
        for (int m = 0; m < MR; ++m) {
            float xv = xs[(rg * MR + m) * CIN + k];
            acc[m][0] += xv * w.x; acc[m][1] += xv * w.y;
            acc[m][2] += xv * w.z; acc[m][3] += xv * w.w;
        }
    }

    float4 bv = make_float4(0.f, 0.f, 0.f, 0.f);
    if (bias) bv = *(const float4*)(bias + c0);

    #pragma unroll
    for (int m = 0; m < MR; ++m) {
        int row = row0 + rg * MR + m;
        if (row >= M) continue;
        float v[4] = { acc[m][0] + bv.x, acc[m][1] + bv.y, acc[m][2] + bv.z, acc[m][3] + bv.w };
        if constexpr (MODE & 1) {
            #pragma unroll
            for (int u = 0; u < 4; ++u) v[u] = silu_f(v[u]);
        }
        if constexpr (sizeof(OT) == 4) {
            *(float4*)((float*)y + (size_t)row * COUT + c0) = make_float4(v[0], v[1], v[2], v[3]);
        } else {
            store_bf4((ushort*)y + (size_t)row * COUT + c0, v[0], v[1], v[2], v[3]);
        }
    }
}

// ---------------------------------------------------------------------------
// Fused embedding (t3 is bf16)
// ---------------------------------------------------------------------------
__global__ __launch_bounds__(256) void fuse_embed_kernel(
    const int* __restrict__ z, const int* __restrict__ ii, const int* __restrict__ jj,
    const float* __restrict__ pt1, const float* __restrict__ pt2,
    const ushort* __restrict__ t3, const float* __restrict__ bias,
    ushort* __restrict__ x, int E)
{
    int idx = blockIdx.x * 256 + threadIdx.x;
    int e = idx >> 5;
    if (e >= E) return;
    int c4 = (idx & 31) * 4;
    int zi = z[ii[e]], zj = z[jj[e]];
    float4 a = *(const float4*)(pt1 + zi * 128 + c4);
    float4 b = *(const float4*)(pt2 + zj * 128 + c4);
    ushort4 t = *(const ushort4*)(t3 + (size_t)e * 128 + c4);
    float4 bb = *(const float4*)(bias + c4);
    store_bf4(x + (size_t)e * 128 + c4,
              silu_f(a.x + b.x + bf2f(t.x) + bb.x), silu_f(a.y + b.y + bf2f(t.y) + bb.y),
              silu_f(a.z + b.z + bf2f(t.z) + bb.z), silu_f(a.w + b.w + bf2f(t.w) + bb.w));
}

// ---------------------------------------------------------------------------
// s1all = sbf(fp32) @ W1[b] for all 4 blocks -> CSR order, interleaved layout
// s1all[pos[t]*32 + b*8 + p] (bf16). Flat div-free float4 staging.
// ---------------------------------------------------------------------------
__global__ __launch_bounds__(256) void s1all_kernel(
    const float* __restrict__ sbf, const float* __restrict__ W1,
    const int* __restrict__ pos, ushort* __restrict__ s1all, int T)
{
    constexpr int TT = 32;                // triplets per block
    constexpr int FL = TT * 42;           // 1344 floats, 336 float4
    __shared__ float s_flat[FL];
    __shared__ float s_w1[4 * 42 * 8];
    __shared__ ushort s_out[TT][4][8];
    const int t0 = blockIdx.x * TT;
    const int tid = threadIdx.x;

    for (int k = tid; k < 4 * 42 * 8; k += 256) s_w1[k] = W1[k];
    // flat, contiguous, 16B-aligned staging (t0*42 elements offset, 1344 % 4 == 0)
    if (t0 + TT <= T) {
        const float4* src = (const float4*)(sbf + (size_t)t0 * 42);
        for (int k = tid; k < FL / 4; k += 256)
            ((float4*)s_flat)[k] = src[k];
    } else {
        const size_t base = (size_t)t0 * 42;
        const size_t tot = (size_t)T * 42;
        for (int k = tid; k < FL; k += 256)
            s_flat[k] = (base + k < tot) ? sbf[base + k] : 0.0f;
    }
    __syncthreads();
    {
        int t = tid >> 3, p = tid & 7;
        const float* row = s_flat + t * 42;
        float a0 = 0.f, a1 = 0.f, a2 = 0.f, a3 = 0.f;
        #pragma unroll
        for (int q = 0; q < 42; ++q) {
            float xv = row[q];
            a0 += xv * s_w1[0 * 336 + q * 8 + p];
            a1 += xv * s_w1[1 * 336 + q * 8 + p];
            a2 += xv * s_w1[2 * 336 + q * 8 + p];
            a3 += xv * s_w1[3 * 336 + q * 8 + p];
        }
        s_out[t][0][p] = f2bf(a0);
        s_out[t][1][p] = f2bf(a1);
        s_out[t][2][p] = f2bf(a2);
        s_out[t][3][p] = f2bf(a3);
    }
    __syncthreads();
    if (tid < 128) {
        int t = tid >> 2, b = tid & 3;      // 4 consecutive lanes share one 64B line
        int gt = t0 + t;
        if (gt < T)
            *(s16x8*)(s1all + ((size_t)pos[gt] * 4 + b) * 8) = *(const s16x8*)s_out[t][b];
    }
}

// ---------------------------------------------------------------------------
// CSR build
// ---------------------------------------------------------------------------
__global__ void count_kernel(const int* __restrict__ seg, int* __restrict__ deg, int T)
{
    int t = blockIdx.x * blockDim.x + threadIdx.x;
    if (t < T) atomicAdd(&deg[seg[t]], 1);
}

__global__ __launch_bounds__(256) void scan1_kernel(const int* __restrict__ deg,
                                                    int* __restrict__ offs,
                                                    int* __restrict__ bsum, int E)
{
    __shared__ int s[256];
    int tid = threadIdx.x;
    int g = blockIdx.x * 256 + tid;
    int v = (g < E) ? deg[g] : 0;
    s[tid] = v;
    __syncthreads();
    for (int d = 1; d < 256; d <<= 1) {
        int t = (tid >= d) ? s[tid - d] : 0;
        __syncthreads();
        s[tid] += t;
        __syncthreads();
    }
    if (g < E) offs[g] = s[tid] - v;
    if (tid == 255) bsum[blockIdx.x] = s[255];
}

__global__ __launch_bounds__(1024) void scan2_kernel(int* __restrict__ bsum, int NB)
{
    __shared__ int s[1024];
    int tid = threadIdx.x;
    int v = (tid < NB) ? bsum[tid] : 0;
    s[tid] = v;
    __syncthreads();
    for (int d = 1; d < 1024; d <<= 1) {
        int t = (tid >= d) ? s[tid - d] : 0;
        __syncthreads();
        s[tid] += t;
        __syncthreads();
    }
    if (tid < NB) bsum[tid] = s[tid] - v;
}

__global__ __launch_bounds__(256) void scan3_kernel(int* __restrict__ offs,
                                                    const int* __restrict__ bsum,
                                                    int E, int T)
{
    int g = blockIdx.x * 256 + threadIdx.x;
    if (g < E) offs[g] += bsum[blockIdx.x];
    if (g == 0) offs[E] = T;
}

// ji-CSR fill: also writes kj_csr directly
__global__ void fill_kernel(const int* __restrict__ idx_ji, const int* __restrict__ idx_kj,
                            const int* __restrict__ offs, int* __restrict__ cursor,
                            int* __restrict__ kj_csr, int* __restrict__ pos, int T)
{
    int t = blockIdx.x * blockDim.x + threadIdx.x;
    if (t >= T) return;
    int ji = idx_ji[t];
    int slot = atomicAdd(&cursor[ji], 1);
    int k = offs[ji] + slot;
    kj_csr[k] = idx_kj[t];
    pos[t] = k;
}

// i-CSR fill: edge list per node
__global__ void fillN_kernel(const int* __restrict__ ii, const int* __restrict__ offs,
                             int* __restrict__ cursor, int* __restrict__ elist, int E)
{
    int e = blockIdx.x * blockDim.x + threadIdx.x;
    if (e >= E) return;
    int n = ii[e];
    int slot = atomicAdd(&cursor[n], 1);
    elist[offs[n] + slot] = e;
}

// ---------------------------------------------------------------------------
// CSR gather (triplet), 2-way unrolled; s1 layout [k][4][8], read b-th slice
// ---------------------------------------------------------------------------
__global__ __launch_bounds__(256) void gather2_kernel(
    const ushort* __restrict__ s1, const float* __restrict__ W2,
    const ushort* __restrict__ xd, const int* __restrict__ kj_csr,
    const int* __restrict__ offs, ushort* __restrict__ out, int E, int boff)
{
    const int lane = threadIdx.x & 63;
    const int e = blockIdx.x * 4 + (threadIdx.x >> 6);
    if (e >= E) return;
    float w2[8];
    #pragma unroll
    for (int p = 0; p < 8; ++p) w2[p] = W2[p * 64 + lane];
    float accA = 0.0f, accB = 0.0f;
    const int k0 = offs[e], k1 = offs[e + 1];
    int k = k0;
    for (; k + 1 < k1; k += 2) {
        s16x8 sv0 = *(const s16x8*)(s1 + (size_t)k * 32 + boff);
        s16x8 sv1 = *(const s16x8*)(s1 + (size_t)(k + 1) * 32 + boff);
        int kj0 = kj_csr[k];
        int kj1 = kj_csr[k + 1];
        float x0 = bf2f(xd[(size_t)kj0 * 64 + lane]);
        float x1 = bf2f(xd[(size_t)kj1 * 64 + lane]);
        float sb0 = bf2f((ushort)sv0[0]) * w2[0] + bf2f((ushort)sv0[1]) * w2[1]
                  + bf2f((ushort)sv0[2]) * w2[2] + bf2f((ushort)sv0[3]) * w2[3]
                  + bf2f((ushort)sv0[4]) * w2[4] + bf2f((ushort)sv0[5]) * w2[5]
                  + bf2f((ushort)sv0[6]) * w2[6] + bf2f((ushort)sv0[7]) * w2[7];
        float sb1 = bf2f((ushort)sv1[0]) * w2[0] + bf2f((ushort)sv1[1]) * w2[1]
                  + bf2f((ushort)sv1[2]) * w2[2] + bf2f((ushort)sv1[3]) * w2[3]
                  + bf2f((ushort)sv1[4]) * w2[4] + bf2f((ushort)sv1[5]) * w2[5]
                  + bf2f((ushort)sv1[6]) * w2[6] + bf2f((ushort)sv1[7]) * w2[7];
        accA += sb0 * x0;
        accB += sb1 * x1;
    }
    if (k < k1) {
        s16x8 sv = *(const s16x8*)(s1 + (size_t)k * 32 + boff);
        int kj = kj_csr[k];
        float sb = bf2f((ushort)sv[0]) * w2[0] + bf2f((ushort)sv[1]) * w2[1]
                 + bf2f((ushort)sv[2]) * w2[2] + bf2f((ushort)sv[3]) * w2[3]
                 + bf2f((ushort)sv[4]) * w2[4] + bf2f((ushort)sv[5]) * w2[5]
                 + bf2f((ushort)sv[6]) * w2[6] + bf2f((ushort)sv[7]) * w2[7];
        accA += sb * bf2f(xd[(size_t)kj * 64 + lane]);
    }
    out[(size_t)e * 64 + lane] = f2bf(accA + accB);
}

// ---------------------------------------------------------------------------
extern "C" void kernel_launch(void* const* d_in, const int* in_sizes, int n_in,
                              void* d_out, int out_size, void* d_ws, size_t ws_size,
                              hipStream_t stream)
{
    const int*   z         = (const int*)  d_in[0];
    const float* dist      = (const float*)d_in[1];
    const float* sbf       = (const float*)d_in[2];
    const int*   ii        = (const int*)  d_in[3];
    const int*   jj        = (const int*)  d_in[4];
    const int*   idx_kj    = (const int*)  d_in[5];
    const int*   idx_ji    = (const int*)  d_in[6];
    const float* emb_table = (const float*)d_in[7];
    const float* W_rbf_emb = (const float*)d_in[8];
    const float* b_rbf_emb = (const float*)d_in[9];
    const float* W_emb     = (const float*)d_in[10];
    const float* b_emb     = (const float*)d_in[11];
    const float* freq      = (const float*)d_in[12];
    const float* Wi_rbf1   = (const float*)d_in[13];
    const float* Wi_rbf2   = (const float*)d_in[14];
    const float* Wi_sbf1   = (const float*)d_in[15];
    const float* Wi_sbf2   = (const float*)d_in[16];
    const float* Wi_kj     = (const float*)d_in[17];
    const float* bi_kj     = (const float*)d_in[18];
    const float* Wi_ji     = (const float*)d_in[19];
    const float* bi_ji     = (const float*)d_in[20];
    const float* Wi_down   = (const float*)d_in[21];
    const float* Wi_up     = (const float*)d_in[22];
    const float* Wi_rb_W1  = (const float*)d_in[23];
    const float* Wi_rb_b1  = (const float*)d_in[24];
    const float* Wi_rb_W2  = (const float*)d_in[25];
    const float* Wi_rb_b2  = (const float*)d_in[26];
    const float* Wi_lin    = (const float*)d_in[27];
    const float* bi_lin    = (const float*)d_in[28];
    const float* Wi_ra_W1  = (const float*)d_in[29];
    const float* Wi_ra_b1  = (const float*)d_in[30];
    const float* Wi_ra_W2  = (const float*)d_in[31];
    const float* Wi_ra_b2  = (const float*)d_in[32];
    const float* Wo_rbf    = (const float*)d_in[33];
    const float* Wo_up     = (const float*)d_in[34];
    const float* Wo_linW   = (const float*)d_in[35];
    const float* Wo_linb   = (const float*)d_in[36];

    const int N = NND, E = NE, T = NT;
    float* ws = (float*)d_ws;
    size_t off = 0;
    float* rbf  = ws + off; off += (size_t)E * 6;
    float* buf0 = ws + off; off += (size_t)E * 128;
    float* buf1 = ws + off; off += (size_t)E * 128;
    float* buf2 = ws + off; off += (size_t)E * 128;
    float* buf3 = ws + off; off += (size_t)E * 64;
    float* buf4 = ws + off; off += (size_t)E * 64;
    int* ideg  = (int*)(ws + off); off += E;
    int* ioffs = (int*)(ws + off); off += E + 1;
    int* icur  = (int*)(ws + off); off += E;
    int* ikj   = (int*)(ws + off); off += T;
    int* ipos  = (int*)(ws + off); off += T;
    int* ibsum = (int*)(ws + off); off += 1024;
    int* ndeg  = (int*)(ws + off); off += N;
    int* noffs = (int*)(ws + off); off += N + 1;
    int* ncur  = (int*)(ws + off); off += N;
    int* nedge = (int*)(ws + off); off += E;
    int* nbsum = (int*)(ws + off); off += 1024;
    float* pt1 = ws + off; off += 95 * 128;
    float* pt2 = ws + off; off += 95 * 128;
    ushort* wt_ji   = (ushort*)(ws + off);
    ushort* wt_kj   = wt_ji   + 4 * 16384;
    ushort* wt_rb1  = wt_kj   + 4 * 16384;
    ushort* wt_rb2  = wt_rb1  + 4 * 16384;
    ushort* wt_lin  = wt_rb2  + 4 * 16384;
    ushort* wt_ra1  = wt_lin  + 4 * 16384;
    ushort* wt_ra2  = wt_ra1  + 4 * 16384;
    ushort* wt_down = wt_ra2  + 4 * 16384;
    ushort* wt_up   = wt_down + 4 * 8192;
    ushort* wt_emb3 = wt_up   + 4 * 8192;
    ushort* wt_oup  = wt_emb3 + 16384;
    ushort* wt_olin = wt_oup  + 5 * 32768;
    off += (7 * 4 * 16384 + 2 * 4 * 8192 + 16384 + 5 * 32768 + 15 * 65536 + 1) / 2;

    ushort* xb     = (ushort*)buf0;
    ushort* xjib   = (ushort*)buf1;
    ushort* rbfhb  = (ushort*)buf2;               // E*128 bf16 rbf_h (embedding scratch)
    ushort* t3b    = (ushort*)buf1;               // E*128 bf16 t3 (then xjib reuses buf1)
    ushort* s1all  = (ushort*)buf2;               // T*4*8 bf16 interleaved (after rbfhb dead)
    ushort* xdb    = (ushort*)buf3;
    ushort* gob    = (ushort*)buf4;
    ushort* nodeb  = (ushort*)buf3;               // N*128 bf16 (aliases xdb, same lifetime as old fp32 node)
    float* P = (float*)d_out;

    const int gridE  = (E + 63) / 64;
    const int gridN  = (N + 63) / 64;
    const int NB_SCAN  = (E + 255) / 256;
    const int NB_SCANN = (N + 255) / 256;

    hipMemsetAsync(d_out, 0, (size_t)N * 256 * 4, stream);

    twt7_kernel<<<7 * 65536 / 256, 256, 0, stream>>>(
        Wi_ji, Wi_kj, Wi_rb_W1, Wi_rb_W2, Wi_lin, Wi_ra_W1, Wi_ra_W2, wt_ji);
    twt_kernel<<<128, 256, 0, stream>>>(Wi_down,  wt_down, 128,  64, 4 * 8192);
    twt_kernel<<<128, 256, 0, stream>>>(Wi_up,    wt_up,    64, 128, 4 * 8192);
    twt_kernel<<<64,  256, 0, stream>>>(W_emb + 256 * 128, wt_emb3, 128, 128, 16384);
    twt_kernel<<<640, 256, 0, stream>>>(Wo_up,   wt_oup,  128, 256, 5 * 32768);
    twt_kernel<<<3840, 256, 0, stream>>>(Wo_linW, wt_olin, 256, 256, 15 * 65536);

    hipMemsetAsync(ideg, 0, (size_t)E * 4, stream);
    count_kernel<<<(T + 255) / 256, 256, 0, stream>>>(idx_ji, ideg, T);
    scan1_kernel<<<NB_SCAN, 256, 0, stream>>>(ideg, ioffs, ibsum, E);
    scan2_kernel<<<1, 1024, 0, stream>>>(ibsum, NB_SCAN);
    scan3_kernel<<<NB_SCAN, 256, 0, stream>>>(ioffs, ibsum, E, T);
    hipMemsetAsync(icur, 0, (size_t)E * 4, stream);
    fill_kernel<<<(T + 255) / 256, 256, 0, stream>>>(idx_ji, idx_kj, ioffs, icur, ikj, ipos, T);

    hipMemsetAsync(ndeg, 0, (size_t)N * 4, stream);
    count_kernel<<<(E + 255) / 256, 256, 0, stream>>>(ii, ndeg, E);
    scan1_kernel<<<NB_SCANN, 256, 0, stream>>>(ndeg, noffs, nbsum, N);
    scan2_kernel<<<1, 1024, 0, stream>>>(nbsum, NB_SCANN);
    scan3_kernel<<<NB_SCANN, 256, 0, stream>>>(noffs, nbsum, N, E);
    hipMemsetAsync(ncur, 0, (size_t)N * 4, stream);
    fillN_kernel<<<(E + 255) / 256, 256, 0, stream>>>(ii, noffs, ncur, nedge, E);

    rbf_kernel<<<(E + 255) / 256, 256, 0, stream>>>(dist, freq, rbf, E);
    // rbf_h (bf16) -> buf2
    lin_kernel<6, 128, 1, ushort><<<gridE, 256, 0, stream>>>(rbf, W_rbf_emb, b_rbf_emb, nullptr, rbfhb, E);
    lin_kernel<128, 128, 0, float><<<2, 256, 0, stream>>>(emb_table, W_emb, nullptr, nullptr, pt1, 95);
    lin_kernel<128, 128, 0, float><<<2, 256, 0, stream>>>(emb_table, W_emb + 128 * 128, nullptr, nullptr, pt2, 95);
    // t3 (bf16) = rbf_h @ W3 -> buf1
    mfma_lin_kernel<128, 128, 0, ushort, float, ushort><<<gridE, 256, 0, stream>>>(
        rbfhb, wt_emb3, nullptr, nullptr, t3b, E);
    fuse_embed_kernel<<<(E * 32 + 255) / 256, 256, 0, stream>>>(z, ii, jj, pt1, pt2, t3b, b_emb, xb, E);
    // s1 for ALL 4 blocks in one pass (buf2 free after mfma_lin consumed rbfhb)
    s1all_kernel<<<(T + 31) / 32, 256, 0, stream>>>(sbf, Wi_sbf1, ipos, s1all, T);

    auto out_block = [&](int b) {
        node_gather_kernel<<<(N + 1) / 2, 256, 0, stream>>>(
            rbf, Wo_rbf + (size_t)b * 6 * 128, xb, noffs, nedge, nodeb, N);
        mfma_out_kernel<<<gridN, 256, 0, stream>>>(
            nodeb, wt_oup + (size_t)b * 32768, wt_olin + (size_t)b * 3 * 65536,
            Wo_linb + (size_t)b * 3 * 256, P, N);
    };

    out_block(0);

    for (int b = 0; b < 4; ++b) {
        mfma_front_kernel<<<gridE, 256, 0, stream>>>(
            xb, wt_ji + (size_t)b * 16384, wt_kj + (size_t)b * 16384,
            wt_down + (size_t)b * 8192,
            bi_ji + b * 128, bi_kj + b * 128,
            rbf, Wi_rbf1 + (size_t)b * 48, Wi_rbf2 + (size_t)b * 1024,
            xjib, xdb, E);
        gather2_kernel<<<(E + 3) / 4, 256, 0, stream>>>(
            s1all, Wi_sbf2 + (size_t)b * 512, xdb, ikj, ioffs, gob, E, b * 8);
        mfma_back_kernel<<<gridE, 256, 0, stream>>>(
            gob, xjib, xb,
            wt_up + (size_t)b * 8192, wt_rb1 + (size_t)b * 16384,
            wt_rb2 + (size_t)b * 16384, wt_lin + (size_t)b * 16384,
            wt_ra1 + (size_t)b * 16384, wt_ra2 + (size_t)b * 16384,
            Wi_rb_b1 + b * 128, Wi_rb_b2 + b * 128, bi_lin + b * 128,
            Wi_ra_b1 + b * 128, Wi_ra_b2 + b * 128,
            xb, E);

        out_block(b + 1);
    }
}

// Round 29
// 1921.514 us; speedup vs baseline: 1.0073x; 1.0073x over previous
//
#include <hip/hip_runtime.h>
#include <hip/hip_bf16.h>

#define NND 20000
#define NE  200000
#define NT  800000

#define SW256(row) (((row) & 7) << 4)
#define SW128(row) (((row) & 7) << 4)

typedef short  s16x8 __attribute__((ext_vector_type(8)));
typedef float  f32x4 __attribute__((ext_vector_type(4)));

__device__ __forceinline__ float silu_f(float v) {
    return v * __builtin_amdgcn_rcpf(1.0f + __expf(-v));
}

__device__ __forceinline__ ushort f2bf(float f) {
    uint u = __float_as_uint(f);
    uint r = (u + 0x7FFFu + ((u >> 16) & 1u)) >> 16;   // RTNE
    return (ushort)r;
}
__device__ __forceinline__ float bf2f(ushort u) {
    return __uint_as_float(((uint)u) << 16);
}
__device__ __forceinline__ uint f2bf_pk(float a, float b) {
    __hip_bfloat162 h = __float22bfloat162_rn(make_float2(a, b));
    return *(uint*)&h;
}
__device__ __forceinline__ void store_bf4(void* p, float v0, float v1, float v2, float v3) {
    uint2 o;
    o.x = f2bf_pk(v0, v1);
    o.y = f2bf_pk(v2, v3);
    *(uint2*)p = o;
}

// ---------------------------------------------------------------------------
// Bessel basis
// ---------------------------------------------------------------------------
__global__ void rbf_kernel(const float* __restrict__ dist, const float* __restrict__ freq,
                           float* __restrict__ rbf, int E)
{
    int e = blockIdx.x * blockDim.x + threadIdx.x;
    if (e >= E) return;
    float d = dist[e] * 0.2f;
    float d5 = d * d; d5 = d5 * d5 * d;
    float env = 1.0f / d + (-28.0f) * d5 + 48.0f * d5 * d + (-21.0f) * d5 * d * d;
    env = (d < 1.0f) ? env : 0.0f;
    float fr[6];
    #pragma unroll
    for (int r = 0; r < 6; ++r) fr[r] = freq[r];
    #pragma unroll
    for (int r = 0; r < 6; ++r)
        rbf[(size_t)e * 6 + r] = env * sinf(fr[r] * d);
}

// ---------------------------------------------------------------------------
// Weight transpose+convert (generic) and 7-way merged version
// ---------------------------------------------------------------------------
__global__ void twt_kernel(const float* __restrict__ W, ushort* __restrict__ Wt,
                           int CIN, int COUT, int total)
{
    int idx = blockIdx.x * 256 + threadIdx.x;
    if (idx >= total) return;
    int per = CIN * COUT;
    int b = idx / per, r = idx % per;
    int k = r / COUT, c = r % COUT;
    Wt[(size_t)b * per + (size_t)c * CIN + k] = f2bf(W[idx]);
}

__global__ void twt7_kernel(const float* __restrict__ s0, const float* __restrict__ s1,
                            const float* __restrict__ s2, const float* __restrict__ s3,
                            const float* __restrict__ s4, const float* __restrict__ s5,
                            const float* __restrict__ s6, ushort* __restrict__ dst)
{
    int idx = blockIdx.x * 256 + threadIdx.x;     // 7 * 65536 total
    int which = idx >> 16;
    int r = idx & 65535;
    const float* s = (which == 0) ? s0 : (which == 1) ? s1 : (which == 2) ? s2 :
                     (which == 3) ? s3 : (which == 4) ? s4 : (which == 5) ? s5 : s6;
    int b = r >> 14;
    int rr = r & 16383;
    int k = rr >> 7, c = rr & 127;
    dst[(size_t)which * 65536 + b * 16384 + c * 128 + k] = f2bf(s[r]);
}

// ---------------------------------------------------------------------------
// bf16 MFMA linear (embedding t3 only). CIN=COUT=128.
// ---------------------------------------------------------------------------
template<int CIN, int COUT, int MODE, typename IT, typename ET, typename OT>
__global__ __launch_bounds__(256) void mfma_lin_kernel(
    const IT* __restrict__ x, const ushort* __restrict__ Wt,
    const float* __restrict__ bias, const ET* __restrict__ extra,
    OT* __restrict__ y, int M)
{
    constexpr int MT = 64;
    constexpr int NF = COUT / 16;
    constexpr int KS = CIN / 32;
    constexpr int PITCH = CIN * 2;
    __shared__ ushort As_u[MT * CIN];
    __shared__ ushort Ws_u[COUT * CIN];
    char* As = (char*)As_u;
    char* Ws = (char*)Ws_u;
    const int tid = threadIdx.x;
    const int row0 = blockIdx.x * MT;
    const bool full = (row0 + MT <= M);

    constexpr int ACH = MT * CIN / 8;
    for (int c = tid; c < ACH; c += 256) {
        int row = c / (CIN / 8);
        int kc  = c % (CIN / 8);
        int grow = row0 + row;
        s16x8 v;
        if (full || grow < M) {
            if constexpr (sizeof(IT) == 4) {
                const float* src = (const float*)x + (size_t)grow * CIN + kc * 8;
                float4 f0 = *(const float4*)(src);
                float4 f1 = *(const float4*)(src + 4);
                v[0] = (short)f2bf(f0.x); v[1] = (short)f2bf(f0.y);
                v[2] = (short)f2bf(f0.z); v[3] = (short)f2bf(f0.w);
                v[4] = (short)f2bf(f1.x); v[5] = (short)f2bf(f1.y);
                v[6] = (short)f2bf(f1.z); v[7] = (short)f2bf(f1.w);
            } else {
                v = *(const s16x8*)((const ushort*)x + (size_t)grow * CIN + kc * 8);
            }
        } else {
            #pragma unroll
            for (int u = 0; u < 8; ++u) v[u] = 0;
        }
        *(s16x8*)(As + ((row * PITCH + kc * 16) ^ SW256(row))) = v;
    }
    constexpr int WCH = COUT * CIN / 8;
    for (int c = tid; c < WCH; c += 256) {
        int col = c / (CIN / 8);
        int kc  = c % (CIN / 8);
        s16x8 v = *(const s16x8*)(Wt + (size_t)col * CIN + kc * 8);
        *(s16x8*)(Ws + ((col * PITCH + kc * 16) ^ SW256(col))) = v;
    }
    __syncthreads();

    const int w = tid >> 6, lane = tid & 63;
    const int l15 = lane & 15, l4 = lane >> 4;
    const int arow = w * 16 + l15;

    f32x4 acc[NF];
    #pragma unroll
    for (int nf = 0; nf < NF; ++nf) acc[nf] = (f32x4){0.f, 0.f, 0.f, 0.f};

    #pragma unroll
    for (int ks = 0; ks < KS; ++ks) {
        const int kbyte = (ks * 32 + l4 * 8) * 2;
        s16x8 a = *(const s16x8*)(As + ((arow * PITCH + kbyte) ^ SW256(arow)));
        #pragma unroll
        for (int nf = 0; nf < NF; ++nf) {
            int col = nf * 16 + l15;
            s16x8 bf = *(const s16x8*)(Ws + ((col * PITCH + kbyte) ^ SW256(col)));
            acc[nf] = __builtin_amdgcn_mfma_f32_16x16x32_bf16(bf, a, acc[nf], 0, 0, 0);
        }
    }

    const int grow = row0 + w * 16 + l15;
    if (grow < M) {
        #pragma unroll
        for (int nf = 0; nf < NF; ++nf) {
            int c0 = nf * 16 + l4 * 4;
            float4 bv = make_float4(0.f, 0.f, 0.f, 0.f);
            if (bias) bv = *(const float4*)(bias + c0);
            float v0 = acc[nf][0] + bv.x, v1 = acc[nf][1] + bv.y;
            float v2 = acc[nf][2] + bv.z, v3 = acc[nf][3] + bv.w;
            if constexpr (MODE & 1) {
                v0 = silu_f(v0); v1 = silu_f(v1); v2 = silu_f(v2); v3 = silu_f(v3);
            }
            if constexpr ((MODE & 4) != 0) {
                if constexpr (sizeof(ET) == 4) {
                    float4 ex = *(const float4*)((const float*)extra + (size_t)grow * COUT + c0);
                    v0 += ex.x; v1 += ex.y; v2 += ex.z; v3 += ex.w;
                } else {
                    ushort4 ex = *(const ushort4*)((const ushort*)extra + (size_t)grow * COUT + c0);
                    v0 += bf2f(ex.x); v1 += bf2f(ex.y); v2 += bf2f(ex.z); v3 += bf2f(ex.w);
                }
            }
            if constexpr (sizeof(OT) == 4) {
                float* o = (float*)y + (size_t)grow * COUT + c0;
                if constexpr (MODE & 8) {
                    float4 cur = *(const float4*)o;
                    v0 += cur.x; v1 += cur.y; v2 += cur.z; v3 += cur.w;
                }
                *(float4*)o = make_float4(v0, v1, v2, v3);
            } else {
                store_bf4((ushort*)y + (size_t)grow * COUT + c0, v0, v1, v2, v3);
            }
        }
    }
}

// ---------------------------------------------------------------------------
// FRONT fused with Wdown register-prefetch (round-25 proven version).
// ---------------------------------------------------------------------------
__global__ __launch_bounds__(256) void mfma_front_kernel(
    const ushort* __restrict__ x,
    const ushort* __restrict__ Wt1, const ushort* __restrict__ Wt2,
    const ushort* __restrict__ Wtd,
    const float* __restrict__ b1, const float* __restrict__ b2,
    const float* __restrict__ rbf, const float* __restrict__ W1r,
    const float* __restrict__ W2r,
    ushort* __restrict__ y1, ushort* __restrict__ yd, int M)
{
    constexpr int PITCH = 256;
    __shared__ ushort A_u[64 * 128];
    __shared__ ushort W1_u[128 * 128];
    __shared__ ushort W2_u[128 * 128];
    char* A = (char*)A_u;
    char* W1s = (char*)W1_u;
    char* W2s = (char*)W2_u;
    const int tid = threadIdx.x;
    const int row0 = blockIdx.x * 64;

    for (int c = tid; c < 1024; c += 256) {
        int row = c >> 4, kc = c & 15;
        s16x8 v = *(const s16x8*)(x + (size_t)(row0 + row) * 128 + kc * 8);
        *(s16x8*)(A + ((row * PITCH + kc * 16) ^ SW256(row))) = v;
    }
    for (int c = tid; c < 2048; c += 256) {
        int col = c >> 4, kc = c & 15;
        int o = (col * PITCH + kc * 16) ^ SW256(col);
        *(s16x8*)(W1s + o) = *(const s16x8*)(Wt1 + (size_t)col * 128 + kc * 8);
        *(s16x8*)(W2s + o) = *(const s16x8*)(Wt2 + (size_t)col * 128 + kc * 8);
    }
    s16x8 wdreg[4];
    #pragma unroll
    for (int i = 0; i < 4; ++i) {
        int c = tid + i * 256;
        wdreg[i] = *(const s16x8*)(Wtd + (size_t)(c >> 4) * 128 + (c & 15) * 8);
    }
    __syncthreads();

    const int w = tid >> 6, lane = tid & 63;
    const int l15 = lane & 15, l4 = lane >> 4;
    const int arow = w * 16 + l15;

    f32x4 acc1[8], acc2[8];
    #pragma unroll
    for (int nf = 0; nf < 8; ++nf) {
        acc1[nf] = (f32x4){0.f, 0.f, 0.f, 0.f};
        acc2[nf] = (f32x4){0.f, 0.f, 0.f, 0.f};
    }
    #pragma unroll
    for (int ks = 0; ks < 4; ++ks) {
        const int kbyte = (ks * 32 + l4 * 8) * 2;
        s16x8 a = *(const s16x8*)(A + ((arow * PITCH + kbyte) ^ SW256(arow)));
        #pragma unroll
        for (int nf = 0; nf < 8; ++nf) {
            int col = nf * 16 + l15;
            int o = (col * PITCH + kbyte) ^ SW256(col);
            s16x8 bf1 = *(const s16x8*)(W1s + o);
            s16x8 bf2 = *(const s16x8*)(W2s + o);
            acc1[nf] = __builtin_amdgcn_mfma_f32_16x16x32_bf16(bf1, a, acc1[nf], 0, 0, 0);
            acc2[nf] = __builtin_amdgcn_mfma_f32_16x16x32_bf16(bf2, a, acc2[nf], 0, 0, 0);
        }
    }
    __syncthreads();

    const int grow = row0 + arow;
    float rv[6];
    #pragma unroll
    for (int q = 0; q < 6; ++q) rv[q] = rbf[(size_t)grow * 6 + q];
    float t8[8];
    #pragma unroll
    for (int p = 0; p < 8; ++p) {
        float s = 0.f;
        #pragma unroll
        for (int q = 0; q < 6; ++q) s += rv[q] * W1r[q * 8 + p];
        t8[p] = s;
    }
    #pragma unroll
    for (int nf = 0; nf < 8; ++nf) {
        int c0 = nf * 16 + l4 * 4;
        float4 bb1 = *(const float4*)(b1 + c0);
        float4 bb2 = *(const float4*)(b2 + c0);
        store_bf4(y1 + (size_t)grow * 128 + c0,
                  silu_f(acc1[nf][0] + bb1.x), silu_f(acc1[nf][1] + bb1.y),
                  silu_f(acc1[nf][2] + bb1.z), silu_f(acc1[nf][3] + bb1.w));
        float r0 = 0.f, r1 = 0.f, r2 = 0.f, r3 = 0.f;
        #pragma unroll
        for (int p = 0; p < 8; ++p) {
            float4 wq = *(const float4*)(W2r + p * 128 + c0);
            float tp = t8[p];
            r0 += tp * wq.x; r1 += tp * wq.y; r2 += tp * wq.z; r3 += tp * wq.w;
        }
        store_bf4(A + ((arow * PITCH + c0 * 2) ^ SW256(arow)),
                  silu_f(acc2[nf][0] + bb2.x) * r0, silu_f(acc2[nf][1] + bb2.y) * r1,
                  silu_f(acc2[nf][2] + bb2.z) * r2, silu_f(acc2[nf][3] + bb2.w) * r3);
    }
    #pragma unroll
    for (int i = 0; i < 4; ++i) {
        int c = tid + i * 256;
        int col = c >> 4, kc = c & 15;
        *(s16x8*)(W1s + ((col * PITCH + kc * 16) ^ SW256(col))) = wdreg[i];
    }
    __syncthreads();

    f32x4 accd[4];
    #pragma unroll
    for (int nf = 0; nf < 4; ++nf) accd[nf] = (f32x4){0.f, 0.f, 0.f, 0.f};
    #pragma unroll
    for (int ks = 0; ks < 4; ++ks) {
        const int kbyte = (ks * 32 + l4 * 8) * 2;
        s16x8 a = *(const s16x8*)(A + ((arow * PITCH + kbyte) ^ SW256(arow)));
        #pragma unroll
        for (int nf = 0; nf < 4; ++nf) {
            int col = nf * 16 + l15;
            s16x8 bf = *(const s16x8*)(W1s + ((col * PITCH + kbyte) ^ SW256(col)));
            accd[nf] = __builtin_amdgcn_mfma_f32_16x16x32_bf16(bf, a, accd[nf], 0, 0, 0);
        }
    }
    #pragma unroll
    for (int nf = 0; nf < 4; ++nf) {
        int c0 = nf * 16 + l4 * 4;
        store_bf4(yd + (size_t)grow * 64 + c0,
                  silu_f(accd[nf][0]), silu_f(accd[nf][1]),
                  silu_f(accd[nf][2]), silu_f(accd[nf][3]));
    }
}

// ---------------------------------------------------------------------------
// BACK fused, wave-column-split, 64-row tiles, double-buffered weight
// prefetch + register prefetch of xji (P1) and x (P4) epilogue operands.
// ---------------------------------------------------------------------------
__global__ __launch_bounds__(256) void mfma_back_kernel(
    const ushort* __restrict__ go, const ushort* __restrict__ xji,
    const ushort* __restrict__ x,
    const ushort* __restrict__ Wup, const ushort* __restrict__ Wrb1,
    const ushort* __restrict__ Wrb2, const ushort* __restrict__ Wlin,
    const ushort* __restrict__ Wra1, const ushort* __restrict__ Wra2,
    const float* __restrict__ b_rb1, const float* __restrict__ b_rb2,
    const float* __restrict__ b_lin, const float* __restrict__ b_ra1,
    const float* __restrict__ b_ra2,
    ushort* __restrict__ xout, int M)
{
    __shared__ ushort A_u[64 * 128];
    __shared__ ushort T_u[64 * 128];
    char* A  = (char*)A_u;
    char* Tb = (char*)T_u;
    const int tid = threadIdx.x;
    const int row0 = blockIdx.x * 64;
    const int w = tid >> 6, lane = tid & 63;
    const int l15 = lane & 15, l4 = lane >> 4;
    const int colbase = w * 32;

    f32x4 acc[8];
    s16x8 wfA[8], wfB[8];
    ushort4 xr[8];

    auto zero_acc = [&]() {
        #pragma unroll
        for (int i = 0; i < 8; ++i) acc[i] = (f32x4){0.f, 0.f, 0.f, 0.f};
    };
    auto load_w8 = [&](s16x8* wf, const ushort* Wg) {
        #pragma unroll
        for (int nfi = 0; nfi < 2; ++nfi)
            #pragma unroll
            for (int ks = 0; ks < 4; ++ks)
                wf[nfi * 4 + ks] = *(const s16x8*)(
                    Wg + (size_t)(colbase + nfi * 16 + l15) * 128 + ks * 32 + l4 * 8);
    };
    auto load_rows = [&](const ushort* src) {
        #pragma unroll
        for (int rt = 0; rt < 4; ++rt) {
            int grow = row0 + rt * 16 + l15;
            #pragma unroll
            for (int nfi = 0; nfi < 2; ++nfi) {
                int c0 = colbase + nfi * 16 + l4 * 4;
                xr[rt * 2 + nfi] = *(const ushort4*)(src + (size_t)grow * 128 + c0);
            }
        }
    };
    auto run_phase = [&](char* Ab, const s16x8* wf) {
        #pragma unroll
        for (int rt = 0; rt < 4; ++rt) {
            int row = rt * 16 + l15;
            #pragma unroll
            for (int ks = 0; ks < 4; ++ks) {
                s16x8 a = *(const s16x8*)(Ab + ((row * 256 + ks * 64 + l4 * 16) ^ SW256(row)));
                acc[rt * 2 + 0] = __builtin_amdgcn_mfma_f32_16x16x32_bf16(wf[0 * 4 + ks], a, acc[rt * 2 + 0], 0, 0, 0);
                acc[rt * 2 + 1] = __builtin_amdgcn_mfma_f32_16x16x32_bf16(wf[1 * 4 + ks], a, acc[rt * 2 + 1], 0, 0, 0);
            }
        }
    };

    // prologue: stage go tile; load Wup frags; prefetch rb1 weights + xji rows
    s16x8 wfUp[4];
    #pragma unroll
    for (int nfi = 0; nfi < 2; ++nfi)
        #pragma unroll
        for (int ks = 0; ks < 2; ++ks)
            wfUp[nfi * 2 + ks] = *(const s16x8*)(
                Wup + (size_t)(colbase + nfi * 16 + l15) * 64 + ks * 32 + l4 * 8);
    for (int c = tid; c < 512; c += 256) {
        int row = c >> 3, kc = c & 7;
        s16x8 v = *(const s16x8*)(go + (size_t)(row0 + row) * 64 + kc * 8);
        *(s16x8*)(Tb + ((row * 128 + kc * 16) ^ SW128(row))) = v;
    }
    load_w8(wfA, Wrb1);
    load_rows(xji);
    __syncthreads();

    // P1: hdd = xji + silu(go @ Wup)
    zero_acc();
    #pragma unroll
    for (int rt = 0; rt < 4; ++rt) {
        int row = rt * 16 + l15;
        #pragma unroll
        for (int ks = 0; ks < 2; ++ks) {
            s16x8 a = *(const s16x8*)(Tb + ((row * 128 + ks * 64 + l4 * 16) ^ SW128(row)));
            acc[rt * 2 + 0] = __builtin_amdgcn_mfma_f32_16x16x32_bf16(wfUp[0 * 2 + ks], a, acc[rt * 2 + 0], 0, 0, 0);
            acc[rt * 2 + 1] = __builtin_amdgcn_mfma_f32_16x16x32_bf16(wfUp[1 * 2 + ks], a, acc[rt * 2 + 1], 0, 0, 0);
        }
    }
    #pragma unroll
    for (int rt = 0; rt < 4; ++rt) {
        int row = rt * 16 + l15;
        #pragma unroll
        for (int nfi = 0; nfi < 2; ++nfi) {
            int c0 = colbase + nfi * 16 + l4 * 4;
            f32x4 v = acc[rt * 2 + nfi];
            ushort4 xj = xr[rt * 2 + nfi];
            store_bf4(A + ((row * 256 + c0 * 2) ^ SW256(row)),
                      bf2f(xj.x) + silu_f(v[0]), bf2f(xj.y) + silu_f(v[1]),
                      bf2f(xj.z) + silu_f(v[2]), bf2f(xj.w) + silu_f(v[3]));
        }
    }
    __syncthreads();

    // P2: t = silu(hdd@rb1+b1)  A -> Tb   (prefetch rb2 into wfB)
    load_w8(wfB, Wrb2);
    zero_acc();
    run_phase(A, wfA);
    #pragma unroll
    for (int rt = 0; rt < 4; ++rt) {
        int row = rt * 16 + l15;
        #pragma unroll
        for (int nfi = 0; nfi < 2; ++nfi) {
            int c0 = colbase + nfi * 16 + l4 * 4;
            f32x4 v = acc[rt * 2 + nfi];
            float4 bb = *(const float4*)(b_rb1 + c0);
            store_bf4(Tb + ((row * 256 + c0 * 2) ^ SW256(row)),
                      silu_f(v[0] + bb.x), silu_f(v[1] + bb.y),
                      silu_f(v[2] + bb.z), silu_f(v[3] + bb.w));
        }
    }
    __syncthreads();

    // P3: hdd += silu(t@rb2+b2)  Tb -> A   (prefetch lin into wfA, x rows into xr)
    load_w8(wfA, Wlin);
    load_rows(x);
    zero_acc();
    run_phase(Tb, wfB);
    #pragma unroll
    for (int rt = 0; rt < 4; ++rt) {
        int row = rt * 16 + l15;
        #pragma unroll
        for (int nfi = 0; nfi < 2; ++nfi) {
            int c0 = colbase + nfi * 16 + l4 * 4;
            f32x4 v = acc[rt * 2 + nfi];
            float4 bb = *(const float4*)(b_rb2 + c0);
            int ao = (row * 256 + c0 * 2) ^ SW256(row);
            ushort4 h = *(const ushort4*)(A + ao);
            store_bf4(A + ao,
                      bf2f(h.x) + silu_f(v[0] + bb.x), bf2f(h.y) + silu_f(v[1] + bb.y),
                      bf2f(h.z) + silu_f(v[2] + bb.z), bf2f(h.w) + silu_f(v[3] + bb.w));
        }
    }
    __syncthreads();

    // P4: hdd2 = silu(hdd@lin+bl) + x   A -> A   (prefetch ra1 into wfB)
    load_w8(wfB, Wra1);
    zero_acc();
    run_phase(A, wfA);
    __syncthreads();   // all reads of A done before overwrite
    #pragma unroll
    for (int rt = 0; rt < 4; ++rt) {
        int row = rt * 16 + l15;
        #pragma unroll
        for (int nfi = 0; nfi < 2; ++nfi) {
            int c0 = colbase + nfi * 16 + l4 * 4;
            f32x4 v = acc[rt * 2 + nfi];
            float4 bb = *(const float4*)(b_lin + c0);
            ushort4 xv = xr[rt * 2 + nfi];
            store_bf4(A + ((row * 256 + c0 * 2) ^ SW256(row)),
                      silu_f(v[0] + bb.x) + bf2f(xv.x), silu_f(v[1] + bb.y) + bf2f(xv.y),
                      silu_f(v[2] + bb.z) + bf2f(xv.z), silu_f(v[3] + bb.w) + bf2f(xv.w));
        }
    }
    __syncthreads();

    // P5: t = silu(hdd2@ra1+a1)  A -> Tb   (prefetch ra2 into wfA)
    load_w8(wfA, Wra2);
    zero_acc();
    run_phase(A, wfB);
    #pragma unroll
    for (int rt = 0; rt < 4; ++rt) {
        int row = rt * 16 + l15;
        #pragma unroll
        for (int nfi = 0; nfi < 2; ++nfi) {
            int c0 = colbase + nfi * 16 + l4 * 4;
            f32x4 v = acc[rt * 2 + nfi];
            float4 bb = *(const float4*)(b_ra1 + c0);
            store_bf4(Tb + ((row * 256 + c0 * 2) ^ SW256(row)),
                      silu_f(v[0] + bb.x), silu_f(v[1] + bb.y),
                      silu_f(v[2] + bb.z), silu_f(v[3] + bb.w));
        }
    }
    __syncthreads();

    // P6: xout = hdd2 + silu(t@ra2+a2)  Tb -> global
    zero_acc();
    run_phase(Tb, wfA);
    #pragma unroll
    for (int rt = 0; rt < 4; ++rt) {
        int row = rt * 16 + l15;
        int grow = row0 + row;
        #pragma unroll
        for (int nfi = 0; nfi < 2; ++nfi) {
            int c0 = colbase + nfi * 16 + l4 * 4;
            f32x4 v = acc[rt * 2 + nfi];
            float4 bb = *(const float4*)(b_ra2 + c0);
            ushort4 h = *(const ushort4*)(A + ((row * 256 + c0 * 2) ^ SW256(row)));
            store_bf4(xout + (size_t)grow * 128 + c0,
                      bf2f(h.x) + silu_f(v[0] + bb.x), bf2f(h.y) + silu_f(v[1] + bb.y),
                      bf2f(h.z) + silu_f(v[2] + bb.z), bf2f(h.w) + silu_f(v[3] + bb.w));
        }
    }
}

// ---------------------------------------------------------------------------
// Node gather (bf16 output — identical rounding to the old fp32->bf16 stage)
// ---------------------------------------------------------------------------
__global__ __launch_bounds__(256) void node_gather_kernel(
    const float* __restrict__ rbf, const float* __restrict__ Wo,
    const ushort* __restrict__ x, const int* __restrict__ noffs,
    const int* __restrict__ nedge, ushort* __restrict__ node, int N)
{
    const int tid = threadIdx.x;
    const int col = tid & 127;
    const int n = blockIdx.x * 2 + (tid >> 7);
    if (n >= N) return;
    float wo[6];
    #pragma unroll
    for (int q = 0; q < 6; ++q) wo[q] = Wo[q * 128 + col];
    float acc = 0.f;
    const int k0 = noffs[n], k1 = noffs[n + 1];
    for (int k = k0; k < k1; ++k) {
        int e = nedge[k];
        const float* rb = rbf + (size_t)e * 6;
        float t = wo[0] * rb[0] + wo[1] * rb[1] + wo[2] * rb[2]
                + wo[3] * rb[3] + wo[4] * rb[4] + wo[5] * rb[5];
        acc += t * bf2f(x[(size_t)e * 128 + col]);
    }
    node[(size_t)n * 128 + col] = f2bf(acc);
}

// ---------------------------------------------------------------------------
// Fused output block chain (round-27 two-buffer version; node input bf16)
// ---------------------------------------------------------------------------
__global__ __launch_bounds__(256) void mfma_out_kernel(
    const ushort* __restrict__ node,
    const ushort* __restrict__ Wup, const ushort* __restrict__ Wlin,
    const float* __restrict__ BL, float* __restrict__ P, int N)
{
    __shared__ ushort A_u[64 * 256];
    __shared__ ushort T_u[64 * 256];
    __shared__ ushort W_u[128 * 128];
    char* A  = (char*)A_u;
    char* Tb = (char*)T_u;
    char* Ws = (char*)W_u;
    const int tid = threadIdx.x;
    const int row0 = blockIdx.x * 64;
    const int w = tid >> 6, lane = tid & 63;
    const int l15 = lane & 15, l4 = lane >> 4;
    const int arow = w * 16 + l15;
    const int grow = row0 + arow;
    const int c_base = l4 * 4;

    f32x4 acc[16];
    s16x8 wreg[8];

    auto prefetch_w = [&](const ushort* base, int stride) {
        #pragma unroll
        for (int i = 0; i < 8; ++i) {
            int c = tid + i * 256;
            int col = c >> 4, kc = c & 15;
            wreg[i] = *(const s16x8*)(base + (size_t)col * stride + kc * 8);
        }
    };
    auto commit_w = [&]() {
        #pragma unroll
        for (int i = 0; i < 8; ++i) {
            int c = tid + i * 256;
            int col = c >> 4, kc = c & 15;
            *(s16x8*)(Ws + ((col * 256 + kc * 16) ^ SW256(col))) = wreg[i];
        }
    };
    auto run8 = [&](char* Ab, int apitch, int kboff, int accoff) {
        #pragma unroll
        for (int ks = 0; ks < 4; ++ks) {
            const int kbw = ks * 64 + l4 * 16;
            s16x8 a = *(const s16x8*)(Ab + ((arow * apitch + kboff + kbw) ^ SW256(arow)));
            #pragma unroll
            for (int nf = 0; nf < 8; ++nf) {
                int col = nf * 16 + l15;
                s16x8 bf = *(const s16x8*)(Ws + ((col * 256 + kbw) ^ SW256(col)));
                acc[accoff + nf] = __builtin_amdgcn_mfma_f32_16x16x32_bf16(bf, a, acc[accoff + nf], 0, 0, 0);
            }
        }
    };

    #pragma unroll
    for (int i = 0; i < 16; ++i) acc[i] = (f32x4){0.f, 0.f, 0.f, 0.f};

    // stage node (bf16) -> Tb
    for (int c = tid; c < 1024; c += 256) {
        int row = c >> 4, kc = c & 15;
        int gr = row0 + row;
        s16x8 v;
        if (gr < N) {
            v = *(const s16x8*)(node + (size_t)gr * 128 + kc * 8);
        } else {
            #pragma unroll
            for (int u = 0; u < 8; ++u) v[u] = 0;
        }
        *(s16x8*)(Tb + ((row * 256 + kc * 16) ^ SW256(row))) = v;
    }
    prefetch_w(Wup, 128);
    __syncthreads();
    commit_w();
    prefetch_w(Wup + 128 * 128, 128);
    __syncthreads();
    run8(Tb, 256, 0, 0);
    __syncthreads();
    commit_w();
    prefetch_w(Wlin, 256);
    __syncthreads();
    run8(Tb, 256, 0, 8);
    #pragma unroll
    for (int nf = 0; nf < 16; ++nf) {
        int c0 = nf * 16 + c_base;
        store_bf4(A + ((arow * 512 + c0 * 2) ^ SW256(arow)),
                  acc[nf][0], acc[nf][1], acc[nf][2], acc[nf][3]);
    }
    __syncthreads();

    char* S = A; char* D = Tb;
    for (int l = 0; l < 3; ++l) {
        #pragma unroll
        for (int i = 0; i < 16; ++i) acc[i] = (f32x4){0.f, 0.f, 0.f, 0.f};
        const ushort* WL = Wlin + (size_t)l * 65536;
        for (int q = 0; q < 4; ++q) {
            int ch = q & 1, kh = q >> 1;
            commit_w();
            if (q < 3) {
                int nq = q + 1;
                prefetch_w(WL + (size_t)(nq & 1) * 128 * 256 + (nq >> 1) * 128, 256);
            } else if (l < 2) {
                prefetch_w(Wlin + (size_t)(l + 1) * 65536, 256);
            }
            __syncthreads();
            run8(S, 512, kh * 256, ch * 8);
            __syncthreads();
        }
        const float* bl = BL + l * 256;
        if (l < 2) {
            #pragma unroll
            for (int nf = 0; nf < 16; ++nf) {
                int c0 = nf * 16 + c_base;
                float4 bb = *(const float4*)(bl + c0);
                store_bf4(D + ((arow * 512 + c0 * 2) ^ SW256(arow)),
                          silu_f(acc[nf][0] + bb.x), silu_f(acc[nf][1] + bb.y),
                          silu_f(acc[nf][2] + bb.z), silu_f(acc[nf][3] + bb.w));
            }
            __syncthreads();
            char* tmp = S; S = D; D = tmp;
        } else if (grow < N) {
            #pragma unroll
            for (int nf = 0; nf < 16; ++nf) {
                int c0 = nf * 16 + c_base;
                float4 bb = *(const float4*)(bl + c0);
                float* o = P + (size_t)grow * 256 + c0;
                float4 cur = *(const float4*)o;
                *(float4*)o = make_float4(cur.x + silu_f(acc[nf][0] + bb.x),
                                          cur.y + silu_f(acc[nf][1] + bb.y),
                                          cur.z + silu_f(acc[nf][2] + bb.z),
                                          cur.w + silu_f(acc[nf][3] + bb.w));
            }
        }
    }
}

// ---------------------------------------------------------------------------
// Generic fp32-in linear with selectable output type (tiny GEMMs only)
// ---------------------------------------------------------------------------
template<int CIN, int COUT, int MODE, typename OT>
__global__ __launch_bounds__(256) void lin_kernel(
    const float* __restrict__ x, const float* __restrict__ W,
    const float* __restrict__ bias, const float* __restrict__ extra,
    OT* __restrict__ y, int M)
{
    constexpr int MT = 64;
    constexpr int CG = COUT / 4;
    constexpr int RG = 256 / CG;
    constexpr int MR = MT / RG;
    __shared__ float xs[MT * CIN];

    const int row0 = blockIdx.x * MT;
    const int tid  = threadIdx.x;
    const int rem  = M - row0;

    if (rem >= MT) {
        const float4* src = (const float4*)(x + (size_t)row0 * CIN);
        constexpr int TOT4 = (MT * CIN) / 4;
        for (int idx = tid; idx < TOT4; idx += 256)
            ((float4*)xs)[idx] = src[idx];
    } else {
        for (int idx = tid; idx < MT * CIN; idx += 256) {
            int r = idx / CIN;
            xs[idx] = (r < rem) ? x[(size_t)(row0 + r) * CIN + (idx % CIN)] : 0.0f;
        }
    }
    __syncthreads();

    const int cg = tid % CG, rg = tid / CG;
    const int c0 = cg * 4;
    float acc[MR][4];
    #pragma unroll
    for (int m = 0; m < MR; ++m) { acc[m][0]=0; acc[m][1]=0; acc[m][2]=0; acc[m][3]=0; }

    for (int k = 0; k < CIN; ++k) {
        float4 w = *(const float4*)(W + (size_t)k * COUT + c0);
        #pragma unroll
        for (int m = 0; m < MR; ++m) {
            float xv = xs[(rg * MR + m) * CIN + k];
            acc[m][0] += xv * w.x; acc[m][1] += xv * w.y;
            acc[m][2] += xv * w.z; acc[m][3] += xv * w.w;
        }
    }

    float4 bv = make_float4(0.f, 0.f, 0.f, 0.f);
    if (bias) bv = *(const float4*)(bias + c0);

    #pragma unroll
    for (int m = 0; m < MR; ++m) {
        int row = row0 + rg * MR + m;
        if (row >= M) continue;
        float v[4] = { acc[m][0] + bv.x, acc[m][1] + bv.y, acc[m][2] + bv.z, acc[m][3] + bv.w };
        if constexpr (MODE & 1) {
            #pragma unroll
            for (int u = 0; u < 4; ++u) v[u] = silu_f(v[u]);
        }
        if constexpr (sizeof(OT) == 4) {
            *(float4*)((float*)y + (size_t)row * COUT + c0) = make_float4(v[0], v[1], v[2], v[3]);
        } else {
            store_bf4((ushort*)y + (size_t)row * COUT + c0, v[0], v[1], v[2], v[3]);
        }
    }
}

// ---------------------------------------------------------------------------
// Fused embedding (t3 is bf16)
// ---------------------------------------------------------------------------
__global__ __launch_bounds__(256) void fuse_embed_kernel(
    const int* __restrict__ z, const int* __restrict__ ii, const int* __restrict__ jj,
    const float* __restrict__ pt1, const float* __restrict__ pt2,
    const ushort* __restrict__ t3, const float* __restrict__ bias,
    ushort* __restrict__ x, int E)
{
    int idx = blockIdx.x * 256 + threadIdx.x;
    int e = idx >> 5;
    if (e >= E) return;
    int c4 = (idx & 31) * 4;
    int zi = z[ii[e]], zj = z[jj[e]];
    float4 a = *(const float4*)(pt1 + zi * 128 + c4);
    float4 b = *(const float4*)(pt2 + zj * 128 + c4);
    ushort4 t = *(const ushort4*)(t3 + (size_t)e * 128 + c4);
    float4 bb = *(const float4*)(bias + c4);
    store_bf4(x + (size_t)e * 128 + c4,
              silu_f(a.x + b.x + bf2f(t.x) + bb.x), silu_f(a.y + b.y + bf2f(t.y) + bb.y),
              silu_f(a.z + b.z + bf2f(t.z) + bb.z), silu_f(a.w + b.w + bf2f(t.w) + bb.w));
}

// ---------------------------------------------------------------------------
// s1all = sbf(fp32) @ W1[b] for all 4 blocks -> CSR order, interleaved layout
// s1all[pos[t]*32 + b*8 + p] (bf16). Flat div-free float4 staging.
// ---------------------------------------------------------------------------
__global__ __launch_bounds__(256) void s1all_kernel(
    const float* __restrict__ sbf, const float* __restrict__ W1,
    const int* __restrict__ pos, ushort* __restrict__ s1all, int T)
{
    constexpr int TT = 32;                // triplets per block
    constexpr int FL = TT * 42;           // 1344 floats, 336 float4
    __shared__ float s_flat[FL];
    __shared__ float s_w1[4 * 42 * 8];
    __shared__ ushort s_out[TT][4][8];
    const int t0 = blockIdx.x * TT;
    const int tid = threadIdx.x;

    for (int k = tid; k < 4 * 42 * 8; k += 256) s_w1[k] = W1[k];
    // flat, contiguous, 16B-aligned staging (t0*42 elements offset, 1344 % 4 == 0)
    if (t0 + TT <= T) {
        const float4* src = (const float4*)(sbf + (size_t)t0 * 42);
        for (int k = tid; k < FL / 4; k += 256)
            ((float4*)s_flat)[k] = src[k];
    } else {
        const size_t base = (size_t)t0 * 42;
        const size_t tot = (size_t)T * 42;
        for (int k = tid; k < FL; k += 256)
            s_flat[k] = (base + k < tot) ? sbf[base + k] : 0.0f;
    }
    __syncthreads();
    {
        int t = tid >> 3, p = tid & 7;
        const float* row = s_flat + t * 42;
        float a0 = 0.f, a1 = 0.f, a2 = 0.f, a3 = 0.f;
        #pragma unroll
        for (int q = 0; q < 42; ++q) {
            float xv = row[q];
            a0 += xv * s_w1[0 * 336 + q * 8 + p];
            a1 += xv * s_w1[1 * 336 + q * 8 + p];
            a2 += xv * s_w1[2 * 336 + q * 8 + p];
            a3 += xv * s_w1[3 * 336 + q * 8 + p];
        }
        s_out[t][0][p] = f2bf(a0);
        s_out[t][1][p] = f2bf(a1);
        s_out[t][2][p] = f2bf(a2);
        s_out[t][3][p] = f2bf(a3);
    }
    __syncthreads();
    if (tid < 128) {
        int t = tid >> 2, b = tid & 3;      // 4 consecutive lanes share one 64B line
        int gt = t0 + t;
        if (gt < T)
            *(s16x8*)(s1all + ((size_t)pos[gt] * 4 + b) * 8) = *(const s16x8*)s_out[t][b];
    }
}

// ---------------------------------------------------------------------------
// CSR build
// ---------------------------------------------------------------------------
__global__ void count_kernel(const int* __restrict__ seg, int* __restrict__ deg, int T)
{
    int t = blockIdx.x * blockDim.x + threadIdx.x;
    if (t < T) atomicAdd(&deg[seg[t]], 1);
}

__global__ __launch_bounds__(256) void scan1_kernel(const int* __restrict__ deg,
                                                    int* __restrict__ offs,
                                                    int* __restrict__ bsum, int E)
{
    __shared__ int s[256];
    int tid = threadIdx.x;
    int g = blockIdx.x * 256 + tid;
    int v = (g < E) ? deg[g] : 0;
    s[tid] = v;
    __syncthreads();
    for (int d = 1; d < 256; d <<= 1) {
        int t = (tid >= d) ? s[tid - d] : 0;
        __syncthreads();
        s[tid] += t;
        __syncthreads();
    }
    if (g < E) offs[g] = s[tid] - v;
    if (tid == 255) bsum[blockIdx.x] = s[255];
}

__global__ __launch_bounds__(1024) void scan2_kernel(int* __restrict__ bsum, int NB)
{
    __shared__ int s[1024];
    int tid = threadIdx.x;
    int v = (tid < NB) ? bsum[tid] : 0;
    s[tid] = v;
    __syncthreads();
    for (int d = 1; d < 1024; d <<= 1) {
        int t = (tid >= d) ? s[tid - d] : 0;
        __syncthreads();
        s[tid] += t;
        __syncthreads();
    }
    if (tid < NB) bsum[tid] = s[tid] - v;
}

__global__ __launch_bounds__(256) void scan3_kernel(int* __restrict__ offs,
                                                    const int* __restrict__ bsum,
                                                    int E, int T)
{
    int g = blockIdx.x * 256 + threadIdx.x;
    if (g < E) offs[g] += bsum[blockIdx.x];
    if (g == 0) offs[E] = T;
}

// ji-CSR fill: also writes kj_csr directly
__global__ void fill_kernel(const int* __restrict__ idx_ji, const int* __restrict__ idx_kj,
                            const int* __restrict__ offs, int* __restrict__ cursor,
                            int* __restrict__ kj_csr, int* __restrict__ pos, int T)
{
    int t = blockIdx.x * blockDim.x + threadIdx.x;
    if (t >= T) return;
    int ji = idx_ji[t];
    int slot = atomicAdd(&cursor[ji], 1);
    int k = offs[ji] + slot;
    kj_csr[k] = idx_kj[t];
    pos[t] = k;
}

// i-CSR fill: edge list per node
__global__ void fillN_kernel(const int* __restrict__ ii, const int* __restrict__ offs,
                             int* __restrict__ cursor, int* __restrict__ elist, int E)
{
    int e = blockIdx.x * blockDim.x + threadIdx.x;
    if (e >= E) return;
    int n = ii[e];
    int slot = atomicAdd(&cursor[n], 1);
    elist[offs[n] + slot] = e;
}

// ---------------------------------------------------------------------------
// CSR gather (triplet), 2-way unrolled; s1 layout [k][4][8], read b-th slice
// ---------------------------------------------------------------------------
__global__ __launch_bounds__(256) void gather2_kernel(
    const ushort* __restrict__ s1, const float* __restrict__ W2,
    const ushort* __restrict__ xd, const int* __restrict__ kj_csr,
    const int* __restrict__ offs, ushort* __restrict__ out, int E, int boff)
{
    const int lane = threadIdx.x & 63;
    const int e = blockIdx.x * 4 + (threadIdx.x >> 6);
    if (e >= E) return;
    float w2[8];
    #pragma unroll
    for (int p = 0; p < 8; ++p) w2[p] = W2[p * 64 + lane];
    float accA = 0.0f, accB = 0.0f;
    const int k0 = offs[e], k1 = offs[e + 1];
    int k = k0;
    for (; k + 1 < k1; k += 2) {
        s16x8 sv0 = *(const s16x8*)(s1 + (size_t)k * 32 + boff);
        s16x8 sv1 = *(const s16x8*)(s1 + (size_t)(k + 1) * 32 + boff);
        int kj0 = kj_csr[k];
        int kj1 = kj_csr[k + 1];
        float x0 = bf2f(xd[(size_t)kj0 * 64 + lane]);
        float x1 = bf2f(xd[(size_t)kj1 * 64 + lane]);
        float sb0 = bf2f((ushort)sv0[0]) * w2[0] + bf2f((ushort)sv0[1]) * w2[1]
                  + bf2f((ushort)sv0[2]) * w2[2] + bf2f((ushort)sv0[3]) * w2[3]
                  + bf2f((ushort)sv0[4]) * w2[4] + bf2f((ushort)sv0[5]) * w2[5]
                  + bf2f((ushort)sv0[6]) * w2[6] + bf2f((ushort)sv0[7]) * w2[7];
        float sb1 = bf2f((ushort)sv1[0]) * w2[0] + bf2f((ushort)sv1[1]) * w2[1]
                  + bf2f((ushort)sv1[2]) * w2[2] + bf2f((ushort)sv1[3]) * w2[3]
                  + bf2f((ushort)sv1[4]) * w2[4] + bf2f((ushort)sv1[5]) * w2[5]
                  + bf2f((ushort)sv1[6]) * w2[6] + bf2f((ushort)sv1[7]) * w2[7];
        accA += sb0 * x0;
        accB += sb1 * x1;
    }
    if (k < k1) {
        s16x8 sv = *(const s16x8*)(s1 + (size_t)k * 32 + boff);
        int kj = kj_csr[k];
        float sb = bf2f((ushort)sv[0]) * w2[0] + bf2f((ushort)sv[1]) * w2[1]
                 + bf2f((ushort)sv[2]) * w2[2] + bf2f((ushort)sv[3]) * w2[3]
                 + bf2f((ushort)sv[4]) * w2[4] + bf2f((ushort)sv[5]) * w2[5]
                 + bf2f((ushort)sv[6]) * w2[6] + bf2f((ushort)sv[7]) * w2[7];
        accA += sb * bf2f(xd[(size_t)kj * 64 + lane]);
    }
    out[(size_t)e * 64 + lane] = f2bf(accA + accB);
}

// ---------------------------------------------------------------------------
extern "C" void kernel_launch(void* const* d_in, const int* in_sizes, int n_in,
                              void* d_out, int out_size, void* d_ws, size_t ws_size,
                              hipStream_t stream)
{
    const int*   z         = (const int*)  d_in[0];
    const float* dist      = (const float*)d_in[1];
    const float* sbf       = (const float*)d_in[2];
    const int*   ii        = (const int*)  d_in[3];
    const int*   jj        = (const int*)  d_in[4];
    const int*   idx_kj    = (const int*)  d_in[5];
    const int*   idx_ji    = (const int*)  d_in[6];
    const float* emb_table = (const float*)d_in[7];
    const float* W_rbf_emb = (const float*)d_in[8];
    const float* b_rbf_emb = (const float*)d_in[9];
    const float* W_emb     = (const float*)d_in[10];
    const float* b_emb     = (const float*)d_in[11];
    const float* freq      = (const float*)d_in[12];
    const float* Wi_rbf1   = (const float*)d_in[13];
    const float* Wi_rbf2   = (const float*)d_in[14];
    const float* Wi_sbf1   = (const float*)d_in[15];
    const float* Wi_sbf2   = (const float*)d_in[16];
    const float* Wi_kj     = (const float*)d_in[17];
    const float* bi_kj     = (const float*)d_in[18];
    const float* Wi_ji     = (const float*)d_in[19];
    const float* bi_ji     = (const float*)d_in[20];
    const float* Wi_down   = (const float*)d_in[21];
    const float* Wi_up     = (const float*)d_in[22];
    const float* Wi_rb_W1  = (const float*)d_in[23];
    const float* Wi_rb_b1  = (const float*)d_in[24];
    const float* Wi_rb_W2  = (const float*)d_in[25];
    const float* Wi_rb_b2  = (const float*)d_in[26];
    const float* Wi_lin    = (const float*)d_in[27];
    const float* bi_lin    = (const float*)d_in[28];
    const float* Wi_ra_W1  = (const float*)d_in[29];
    const float* Wi_ra_b1  = (const float*)d_in[30];
    const float* Wi_ra_W2  = (const float*)d_in[31];
    const float* Wi_ra_b2  = (const float*)d_in[32];
    const float* Wo_rbf    = (const float*)d_in[33];
    const float* Wo_up     = (const float*)d_in[34];
    const float* Wo_linW   = (const float*)d_in[35];
    const float* Wo_linb   = (const float*)d_in[36];

    const int N = NND, E = NE, T = NT;
    float* ws = (float*)d_ws;
    size_t off = 0;
    float* rbf  = ws + off; off += (size_t)E * 6;
    float* buf0 = ws + off; off += (size_t)E * 128;
    float* buf1 = ws + off; off += (size_t)E * 128;
    float* buf2 = ws + off; off += (size_t)E * 128;
    float* buf3 = ws + off; off += (size_t)E * 64;
    float* buf4 = ws + off; off += (size_t)E * 64;
    int* ideg  = (int*)(ws + off); off += E;
    int* ioffs = (int*)(ws + off); off += E + 1;
    int* icur  = (int*)(ws + off); off += E;
    int* ikj   = (int*)(ws + off); off += T;
    int* ipos  = (int*)(ws + off); off += T;
    int* ibsum = (int*)(ws + off); off += 1024;
    int* ndeg  = (int*)(ws + off); off += N;
    int* noffs = (int*)(ws + off); off += N + 1;
    int* ncur  = (int*)(ws + off); off += N;
    int* nedge = (int*)(ws + off); off += E;
    int* nbsum = (int*)(ws + off); off += 1024;
    float* pt1 = ws + off; off += 95 * 128;
    float* pt2 = ws + off; off += 95 * 128;
    ushort* wt_ji   = (ushort*)(ws + off);
    ushort* wt_kj   = wt_ji   + 4 * 16384;
    ushort* wt_rb1  = wt_kj   + 4 * 16384;
    ushort* wt_rb2  = wt_rb1  + 4 * 16384;
    ushort* wt_lin  = wt_rb2  + 4 * 16384;
    ushort* wt_ra1  = wt_lin  + 4 * 16384;
    ushort* wt_ra2  = wt_ra1  + 4 * 16384;
    ushort* wt_down = wt_ra2  + 4 * 16384;
    ushort* wt_up   = wt_down + 4 * 8192;
    ushort* wt_emb3 = wt_up   + 4 * 8192;
    ushort* wt_oup  = wt_emb3 + 16384;
    ushort* wt_olin = wt_oup  + 5 * 32768;
    off += (7 * 4 * 16384 + 2 * 4 * 8192 + 16384 + 5 * 32768 + 15 * 65536 + 1) / 2;

    ushort* xb     = (ushort*)buf0;
    ushort* xjib   = (ushort*)buf1;
    ushort* rbfhb  = (ushort*)buf2;               // E*128 bf16 rbf_h (embedding scratch)
    ushort* t3b    = (ushort*)buf1;               // E*128 bf16 t3 (then xjib reuses buf1)
    ushort* s1all  = (ushort*)buf2;               // T*4*8 bf16 interleaved (after rbfhb dead)
    ushort* xdb    = (ushort*)buf3;
    ushort* gob    = (ushort*)buf4;
    ushort* nodeb  = (ushort*)buf3;               // N*128 bf16 (aliases xdb, same lifetime)
    float* P = (float*)d_out;

    const int gridE  = (E + 63) / 64;
    const int gridN  = (N + 63) / 64;
    const int NB_SCAN  = (E + 255) / 256;
    const int NB_SCANN = (N + 255) / 256;

    hipMemsetAsync(d_out, 0, (size_t)N * 256 * 4, stream);

    twt7_kernel<<<7 * 65536 / 256, 256, 0, stream>>>(
        Wi_ji, Wi_kj, Wi_rb_W1, Wi_rb_W2, Wi_lin, Wi_ra_W1, Wi_ra_W2, wt_ji);
    twt_kernel<<<128, 256, 0, stream>>>(Wi_down,  wt_down, 128,  64, 4 * 8192);
    twt_kernel<<<128, 256, 0, stream>>>(Wi_up,    wt_up,    64, 128, 4 * 8192);
    twt_kernel<<<64,  256, 0, stream>>>(W_emb + 256 * 128, wt_emb3, 128, 128, 16384);
    twt_kernel<<<640, 256, 0, stream>>>(Wo_up,   wt_oup,  128, 256, 5 * 32768);
    twt_kernel<<<3840, 256, 0, stream>>>(Wo_linW, wt_olin, 256, 256, 15 * 65536);

    hipMemsetAsync(ideg, 0, (size_t)E * 4, stream);
    count_kernel<<<(T + 255) / 256, 256, 0, stream>>>(idx_ji, ideg, T);
    scan1_kernel<<<NB_SCAN, 256, 0, stream>>>(ideg, ioffs, ibsum, E);
    scan2_kernel<<<1, 1024, 0, stream>>>(ibsum, NB_SCAN);
    scan3_kernel<<<NB_SCAN, 256, 0, stream>>>(ioffs, ibsum, E, T);
    hipMemsetAsync(icur, 0, (size_t)E * 4, stream);
    fill_kernel<<<(T + 255) / 256, 256, 0, stream>>>(idx_ji, idx_kj, ioffs, icur, ikj, ipos, T);

    hipMemsetAsync(ndeg, 0, (size_t)N * 4, stream);
    count_kernel<<<(E + 255) / 256, 256, 0, stream>>>(ii, ndeg, E);
    scan1_kernel<<<NB_SCANN, 256, 0, stream>>>(ndeg, noffs, nbsum, N);
    scan2_kernel<<<1, 1024, 0, stream>>>(nbsum, NB_SCANN);
    scan3_kernel<<<NB_SCANN, 256, 0, stream>>>(noffs, nbsum, N, E);
    hipMemsetAsync(ncur, 0, (size_t)N * 4, stream);
    fillN_kernel<<<(E + 255) / 256, 256, 0, stream>>>(ii, noffs, ncur, nedge, E);

    rbf_kernel<<<(E + 255) / 256, 256, 0, stream>>>(dist, freq, rbf, E);
    // rbf_h (bf16) -> buf2
    lin_kernel<6, 128, 1, ushort><<<gridE, 256, 0, stream>>>(rbf, W_rbf_emb, b_rbf_emb, nullptr, rbfhb, E);
    lin_kernel<128, 128, 0, float><<<2, 256, 0, stream>>>(emb_table, W_emb, nullptr, nullptr, pt1, 95);
    lin_kernel<128, 128, 0, float><<<2, 256, 0, stream>>>(emb_table, W_emb + 128 * 128, nullptr, nullptr, pt2, 95);
    // t3 (bf16) = rbf_h @ W3 -> buf1
    mfma_lin_kernel<128, 128, 0, ushort, float, ushort><<<gridE, 256, 0, stream>>>(
        rbfhb, wt_emb3, nullptr, nullptr, t3b, E);
    fuse_embed_kernel<<<(E * 32 + 255) / 256, 256, 0, stream>>>(z, ii, jj, pt1, pt2, t3b, b_emb, xb, E);
    // s1 for ALL 4 blocks in one pass (buf2 free after mfma_lin consumed rbfhb)
    s1all_kernel<<<(T + 31) / 32, 256, 0, stream>>>(sbf, Wi_sbf1, ipos, s1all, T);

    auto out_block = [&](int b) {
        node_gather_kernel<<<(N + 1) / 2, 256, 0, stream>>>(
            rbf, Wo_rbf + (size_t)b * 6 * 128, xb, noffs, nedge, nodeb, N);
        mfma_out_kernel<<<gridN, 256, 0, stream>>>(
            nodeb, wt_oup + (size_t)b * 32768, wt_olin + (size_t)b * 3 * 65536,
            Wo_linb + (size_t)b * 3 * 256, P, N);
    };

    out_block(0);

    for (int b = 0; b < 4; ++b) {
        mfma_front_kernel<<<gridE, 256, 0, stream>>>(
            xb, wt_ji + (size_t)b * 16384, wt_kj + (size_t)b * 16384,
            wt_down + (size_t)b * 8192,
            bi_ji + b * 128, bi_kj + b * 128,
            rbf, Wi_rbf1 + (size_t)b * 48, Wi_rbf2 + (size_t)b * 1024,
            xjib, xdb, E);
        gather2_kernel<<<(E + 3) / 4, 256, 0, stream>>>(
            s1all, Wi_sbf2 + (size_t)b * 512, xdb, ikj, ioffs, gob, E, b * 8);
        mfma_back_kernel<<<gridE, 256, 0, stream>>>(
            gob, xjib, xb,
            wt_up + (size_t)b * 8192, wt_rb1 + (size_t)b * 16384,
            wt_rb2 + (size_t)b * 16384, wt_lin + (size_t)b * 16384,
            wt_ra1 + (size_t)b * 16384, wt_ra2 + (size_t)b * 16384,
            Wi_rb_b1 + b * 128, Wi_rb_b2 + b * 128, bi_lin + b * 128,
            Wi_ra_b1 + b * 128, Wi_ra_b2 + b * 128,
            xb, E);

        out_block(b + 1);
    }
}